// Round 2
// baseline (8998.449 us; speedup 1.0000x reference)
//
#include <hip/hip_runtime.h>
#include <math.h>

// Problem constants
#define Bdim 4
#define Sdim 2048
#define Ddim 1024
#define Hdim 16
#define HDdim 64

typedef unsigned long long u64;

// ---------------------------------------------------------------------------
// fake-quant helpers
// ---------------------------------------------------------------------------
__device__ __forceinline__ float qdq_f(float x, float amax) {
  // matches: s = max(absmax/127, 1e-8); clip(round(x/s), -128, 127) * s
  float s = fmaxf(amax / 127.0f, 1e-8f);
  float r = rintf(x / s);               // round-half-even == jnp.round
  r = fminf(fmaxf(r, -128.0f), 127.0f);
  return r * s;
}

__device__ __forceinline__ void atomicMaxF(float* a, float v) {
  // valid for non-negative floats: IEEE bits order like ints
  atomicMax((int*)a, __float_as_int(v));
}

// block = 256 threads
__device__ __forceinline__ float blockMax256(float v) {
  __shared__ float sred[4];
  #pragma unroll
  for (int o = 32; o > 0; o >>= 1) v = fmaxf(v, __shfl_xor(v, o));
  if ((threadIdx.x & 63) == 0) sred[threadIdx.x >> 6] = v;
  __syncthreads();
  return fmaxf(fmaxf(sred[0], sred[1]), fmaxf(sred[2], sred[3]));
}

// ---------------------------------------------------------------------------
// scalar init (ws is poisoned 0xAA every call)
// ---------------------------------------------------------------------------
__global__ void init_scalars(float* s) { s[threadIdx.x] = 0.0f; }  // <<<1,64>>>

// ---------------------------------------------------------------------------
// absmax reduction (grid-stride)
// ---------------------------------------------------------------------------
__global__ __launch_bounds__(256) void absmax_kernel(const float* __restrict__ x,
                                                     u64 n, float* __restrict__ amax) {
  u64 i = (u64)blockIdx.x * 256 + threadIdx.x;
  u64 stride = (u64)gridDim.x * 256;
  float m = 0.0f;
  for (; i < n; i += stride) m = fmaxf(m, fabsf(x[i]));
  m = blockMax256(m);
  if (threadIdx.x == 0) atomicMaxF(amax, m);
}

// ---------------------------------------------------------------------------
// LayerNorm (one block per row of 1024), optional input qdq, output absmax
// ---------------------------------------------------------------------------
__global__ __launch_bounds__(256) void ln_kernel(
    const float* __restrict__ x, const float* __restrict__ g,
    const float* __restrict__ beta, const float* __restrict__ inAmax,
    float* __restrict__ y, float* __restrict__ amaxOut)
{
  __shared__ float sred[4];
  __shared__ float smv[2];
  const int tid = threadIdx.x;
  const u64 row = blockIdx.x;
  const float* xr = x + row * Ddim;
  float* yr = y + row * Ddim;
  float aIn = inAmax ? *inAmax : 0.0f;

  float vals[4];
  float sum = 0.0f;
  #pragma unroll
  for (int i = 0; i < 4; i++) {
    float v = xr[tid + (i << 8)];
    if (inAmax) v = qdq_f(v, aIn);
    vals[i] = v;
    sum += v;
  }
  #pragma unroll
  for (int o = 32; o > 0; o >>= 1) sum += __shfl_xor(sum, o);
  if ((tid & 63) == 0) sred[tid >> 6] = sum;
  __syncthreads();
  if (tid == 0) smv[0] = (sred[0] + sred[1] + sred[2] + sred[3]) * (1.0f / 1024.0f);
  __syncthreads();
  const float mean = smv[0];

  float dev = 0.0f;
  #pragma unroll
  for (int i = 0; i < 4; i++) { float d = vals[i] - mean; dev += d * d; }
  #pragma unroll
  for (int o = 32; o > 0; o >>= 1) dev += __shfl_xor(dev, o);
  if ((tid & 63) == 0) sred[tid >> 6] = dev;
  __syncthreads();
  if (tid == 0) {
    float var = (sred[0] + sred[1] + sred[2] + sred[3]) * (1.0f / 1024.0f);
    smv[1] = 1.0f / sqrtf(var + 1e-5f);
  }
  __syncthreads();
  const float inv = smv[1];

  float lmax = 0.0f;
  #pragma unroll
  for (int i = 0; i < 4; i++) {
    int c = tid + (i << 8);
    float ov = (vals[i] - mean) * inv * g[c] + beta[c];
    yr[c] = ov;
    lmax = fmaxf(lmax, fabsf(ov));
  }
  #pragma unroll
  for (int o = 32; o > 0; o >>= 1) lmax = fmaxf(lmax, __shfl_xor(lmax, o));
  __syncthreads();                     // sred reuse barrier
  if ((tid & 63) == 0) sred[tid >> 6] = lmax;
  __syncthreads();
  if (tid == 0)
    atomicMaxF(amaxOut, fmaxf(fmaxf(sred[0], sred[1]), fmaxf(sred[2], sred[3])));
}

// ---------------------------------------------------------------------------
// GEMM: C[M,N] = qdqA(A[M,K]) @ qdqB(B[N,K])^T + bias[N]
// 64x64 tile, BK=16, 4x4 micro-tile per thread, fq applied at LDS fill.
// amaxA/amaxB nullable -> skip fq for that operand.
// ---------------------------------------------------------------------------
__global__ __launch_bounds__(256) void gemm_tn(
    const float* __restrict__ A, const float* __restrict__ Bm,
    const float* __restrict__ bias, float* __restrict__ C,
    int M, int N, int K,
    const float* __restrict__ amaxA, const float* __restrict__ amaxB)
{
  __shared__ __align__(16) float As[16][68];   // pitch 68: 16B aligned, <=2-way banks
  __shared__ __align__(16) float Bs[16][68];
  const int tid = threadIdx.x;
  const int m0 = blockIdx.y << 6, n0 = blockIdx.x << 6;
  const float aA = amaxA ? *amaxA : 0.0f;
  const float aB = amaxB ? *amaxB : 0.0f;
  const int tx = tid & 15, ty = tid >> 4;

  float acc[4][4] = {};
  for (int k0 = 0; k0 < K; k0 += 16) {
    #pragma unroll
    for (int i = 0; i < 4; i++) {
      int flat = tid + (i << 8);
      int r = flat >> 4, c = flat & 15;
      float av = A[(u64)(m0 + r) * K + k0 + c];
      if (amaxA) av = qdq_f(av, aA);
      As[c][r] = av;
      float bv = Bm[(u64)(n0 + r) * K + k0 + c];
      if (amaxB) bv = qdq_f(bv, aB);
      Bs[c][r] = bv;
    }
    __syncthreads();
    #pragma unroll
    for (int k = 0; k < 16; k++) {
      float4 a4 = *(const float4*)&As[k][ty << 2];
      float4 b4 = *(const float4*)&Bs[k][tx << 2];
      float av[4] = {a4.x, a4.y, a4.z, a4.w};
      float bv[4] = {b4.x, b4.y, b4.z, b4.w};
      #pragma unroll
      for (int i = 0; i < 4; i++)
        #pragma unroll
        for (int j = 0; j < 4; j++)
          acc[i][j] += av[i] * bv[j];
    }
    __syncthreads();
  }
  #pragma unroll
  for (int i = 0; i < 4; i++) {
    u64 off = (u64)(m0 + (ty << 2) + i) * N + n0 + (tx << 2);
    float4 o;
    o.x = acc[i][0] + bias[n0 + (tx << 2) + 0];
    o.y = acc[i][1] + bias[n0 + (tx << 2) + 1];
    o.z = acc[i][2] + bias[n0 + (tx << 2) + 2];
    o.w = acc[i][3] + bias[n0 + (tx << 2) + 3];
    *(float4*)&C[off] = o;
  }
}

// ---------------------------------------------------------------------------
// RoPE in-place on q and k, layout (B,S,H,HD); pair (i, i+32), angle = s*inv(i)
// ---------------------------------------------------------------------------
__global__ __launch_bounds__(256) void rope_kernel(float* __restrict__ q,
                                                   float* __restrict__ k) {
  u64 idx = (u64)blockIdx.x * 256 + threadIdx.x;  // B*S*H*32 = 2^22 total
  int i = (int)(idx & 31);
  int h = (int)((idx >> 5) & 15);
  int s = (int)((idx >> 9) & 2047);
  int b = (int)(idx >> 20);
  float inv = (float)pow(10000.0, -(double)i / 32.0);
  float ang = (float)s * inv;
  float cs = cosf(ang), sn = sinf(ang);
  u64 base = ((u64)(b * Sdim + s)) * Ddim + (u64)h * HDdim + i;
  float x1 = q[base], x2 = q[base + 32];
  q[base]      = x1 * cs - x2 * sn;
  q[base + 32] = x1 * sn + x2 * cs;
  x1 = k[base]; x2 = k[base + 32];
  k[base]      = x1 * cs - x2 * sn;
  k[base + 32] = x1 * sn + x2 * cs;
}

// ---------------------------------------------------------------------------
// Flash attention (fp32): one block = (b,h, 64 q-rows). Online softmax.
// P overwrites Ks after a barrier to stay at 3x 17KB LDS (<64KB static limit).
// ---------------------------------------------------------------------------
__global__ __launch_bounds__(256) void attn_kernel(
    const float* __restrict__ Q, const float* __restrict__ K,
    const float* __restrict__ V, float* __restrict__ O)
{
  __shared__ __align__(16) float Qs[64][68];
  __shared__ __align__(16) float Ks[64][68];   // reused as P after sync
  __shared__ __align__(16) float Vs[64][68];
  const int tid = threadIdx.x;
  const int b = blockIdx.y >> 4, h = blockIdx.y & 15;
  const int q0 = blockIdx.x << 6;
  const u64 baseBH = ((u64)b * Sdim) * Ddim + (u64)h * HDdim;

  #pragma unroll
  for (int i = 0; i < 16; i++) {
    int flat = tid + (i << 8);
    int r = flat >> 6, c = flat & 63;
    Qs[r][c] = Q[baseBH + (u64)(q0 + r) * Ddim + c];
  }

  const int rg = tid >> 4, cg = tid & 15;   // rows rg*4.., cols/dims cg*4..
  float m_run[4], l_run[4], oacc[4][4];
  #pragma unroll
  for (int i = 0; i < 4; i++) {
    m_run[i] = -INFINITY; l_run[i] = 0.0f;
    #pragma unroll
    for (int j = 0; j < 4; j++) oacc[i][j] = 0.0f;
  }

  for (int j0 = 0; j0 < Sdim; j0 += 64) {
    __syncthreads();                           // prev PV done before overwrite
    #pragma unroll
    for (int i = 0; i < 16; i++) {
      int flat = tid + (i << 8);
      int r = flat >> 6, c = flat & 63;
      u64 gidx = baseBH + (u64)(j0 + r) * Ddim + c;
      Ks[r][c] = K[gidx];
      Vs[r][c] = V[gidx];
    }
    __syncthreads();

    // scores: sc[i][j] = sum_k Qs[rg*4+i][k]*Ks[cg*4+j][k]; kk swizzled by cg
    float sc[4][4] = {};
    #pragma unroll
    for (int mm = 0; mm < 16; mm++) {
      int kk = ((mm + cg) & 15) << 2;
      float qa[4][4], ka[4][4];
      #pragma unroll
      for (int i = 0; i < 4; i++) {
        float4 t = *(const float4*)&Qs[(rg << 2) + i][kk];
        qa[i][0] = t.x; qa[i][1] = t.y; qa[i][2] = t.z; qa[i][3] = t.w;
      }
      #pragma unroll
      for (int j = 0; j < 4; j++) {
        float4 t = *(const float4*)&Ks[(cg << 2) + j][kk];
        ka[j][0] = t.x; ka[j][1] = t.y; ka[j][2] = t.z; ka[j][3] = t.w;
      }
      #pragma unroll
      for (int i = 0; i < 4; i++)
        #pragma unroll
        for (int j = 0; j < 4; j++)
          #pragma unroll
          for (int t = 0; t < 4; t++)
            sc[i][j] += qa[i][t] * ka[j][t];
    }

    // online softmax update (per row; 16 cg lanes hold identical row state)
    float p[4][4], alpha[4];
    #pragma unroll
    for (int i = 0; i < 4; i++) {
      #pragma unroll
      for (int j = 0; j < 4; j++) sc[i][j] *= 0.125f;   // 1/sqrt(64)
      float mx = fmaxf(fmaxf(sc[i][0], sc[i][1]), fmaxf(sc[i][2], sc[i][3]));
      #pragma unroll
      for (int o = 8; o >= 1; o >>= 1) mx = fmaxf(mx, __shfl_xor(mx, o));
      float m_new = fmaxf(m_run[i], mx);
      alpha[i] = expf(m_run[i] - m_new);
      m_run[i] = m_new;
      float rs = 0.0f;
      #pragma unroll
      for (int j = 0; j < 4; j++) { p[i][j] = expf(sc[i][j] - m_new); rs += p[i][j]; }
      #pragma unroll
      for (int o = 8; o >= 1; o >>= 1) rs += __shfl_xor(rs, o);
      l_run[i] = l_run[i] * alpha[i] + rs;
    }

    __syncthreads();                           // all Ks reads done
    #pragma unroll
    for (int i = 0; i < 4; i++) {
      *(float4*)&Ks[(rg << 2) + i][cg << 2] =
          make_float4(p[i][0], p[i][1], p[i][2], p[i][3]);
      #pragma unroll
      for (int j = 0; j < 4; j++) oacc[i][j] *= alpha[i];
    }
    __syncthreads();

    // PV: oacc[i][j] += sum_t P[rg*4+i][t] * Vs[t][cg*4+j]
    #pragma unroll
    for (int t0 = 0; t0 < 64; t0 += 4) {
      float pa[4][4], va[4][4];
      #pragma unroll
      for (int i = 0; i < 4; i++) {
        float4 t = *(const float4*)&Ks[(rg << 2) + i][t0];
        pa[i][0] = t.x; pa[i][1] = t.y; pa[i][2] = t.z; pa[i][3] = t.w;
      }
      #pragma unroll
      for (int tt = 0; tt < 4; tt++) {
        float4 t = *(const float4*)&Vs[t0 + tt][cg << 2];
        va[tt][0] = t.x; va[tt][1] = t.y; va[tt][2] = t.z; va[tt][3] = t.w;
      }
      #pragma unroll
      for (int i = 0; i < 4; i++)
        #pragma unroll
        for (int j = 0; j < 4; j++)
          #pragma unroll
          for (int tt = 0; tt < 4; tt++)
            oacc[i][j] += pa[i][tt] * va[tt][j];
    }
  }

  #pragma unroll
  for (int i = 0; i < 4; i++) {
    float invl = 1.0f / l_run[i];
    *(float4*)&O[baseBH + (u64)(q0 + (rg << 2) + i) * Ddim + (cg << 2)] =
        make_float4(oacc[i][0] * invl, oacc[i][1] * invl,
                    oacc[i][2] * invl, oacc[i][3] * invl);
  }
}

// ---------------------------------------------------------------------------
// elementwise stages
// ---------------------------------------------------------------------------
__global__ __launch_bounds__(256) void add_qdq_kernel(
    const float* __restrict__ a, const float* __restrict__ amaxA,
    const float* __restrict__ x, float* __restrict__ outp, u64 n,
    float* __restrict__ amaxOut)
{
  const float aA = *amaxA;
  u64 i = (u64)blockIdx.x * 256 + threadIdx.x;
  u64 stride = (u64)gridDim.x * 256;
  float m = 0.0f;
  for (; i < n; i += stride) {
    float t = qdq_f(a[i], aA) + x[i];
    outp[i] = t;
    m = fmaxf(m, fabsf(t));
  }
  m = blockMax256(m);
  if (threadIdx.x == 0) atomicMaxF(amaxOut, m);
}

__global__ __launch_bounds__(256) void gelu_kernel(float* __restrict__ x, u64 n,
                                                   float* __restrict__ amaxOut) {
  u64 i = (u64)blockIdx.x * 256 + threadIdx.x;
  u64 stride = (u64)gridDim.x * 256;
  float m = 0.0f;
  for (; i < n; i += stride) {
    float v = x[i];
    float gv = 0.5f * v * (1.0f + erff(v * 0.70710678118654752440f));
    x[i] = gv;
    m = fmaxf(m, fabsf(gv));
  }
  m = blockMax256(m);
  if (threadIdx.x == 0) atomicMaxF(amaxOut, m);
}

__global__ __launch_bounds__(256) void final_add_kernel(
    const float* __restrict__ hraw, const float* __restrict__ t,
    const float* __restrict__ amaxT, float* __restrict__ u, u64 n,
    float* __restrict__ amaxOut)
{
  const float aT = *amaxT;
  u64 i = (u64)blockIdx.x * 256 + threadIdx.x;
  u64 stride = (u64)gridDim.x * 256;
  float m = 0.0f;
  for (; i < n; i += stride) {
    float v = hraw[i] + qdq_f(t[i], aT);
    u[i] = v;
    m = fmaxf(m, fabsf(v));
  }
  m = blockMax256(m);
  if (threadIdx.x == 0) atomicMaxF(amaxOut, m);
}

__global__ __launch_bounds__(256) void qdq_out_kernel(
    const float* __restrict__ u, const float* __restrict__ amaxU,
    float* __restrict__ o, u64 n)
{
  const float aU = *amaxU;
  u64 i = (u64)blockIdx.x * 256 + threadIdx.x;
  u64 stride = (u64)gridDim.x * 256;
  for (; i < n; i += stride) o[i] = qdq_f(u[i], aU);
}

// ---------------------------------------------------------------------------
// launch
// ---------------------------------------------------------------------------
extern "C" void kernel_launch(void* const* d_in, const int* in_sizes, int n_in,
                              void* d_out, int out_size, void* d_ws, size_t ws_size,
                              hipStream_t stream)
{
  const float* x   = (const float*)d_in[0];
  const float* g1  = (const float*)d_in[1];
  const float* bn1 = (const float*)d_in[2];
  const float* Wq  = (const float*)d_in[3];
  const float* bq  = (const float*)d_in[4];
  const float* Wk  = (const float*)d_in[5];
  const float* bk  = (const float*)d_in[6];
  const float* Wv  = (const float*)d_in[7];
  const float* bv  = (const float*)d_in[8];
  const float* Wo  = (const float*)d_in[9];
  const float* bo  = (const float*)d_in[10];
  const float* g2  = (const float*)d_in[11];
  const float* bn2 = (const float*)d_in[12];
  const float* W1  = (const float*)d_in[13];
  const float* bf1 = (const float*)d_in[14];
  const float* W2  = (const float*)d_in[15];
  const float* bf2 = (const float*)d_in[16];
  float* out = (float*)d_out;

  const u64 NBSD = (u64)Bdim * Sdim * Ddim;   // 8388608
  // ws layout (192 MiB + 1 KiB): [Sc: 256 floats][U0: NBSD][U1: NBSD][F: 4*NBSD]
  // d_out doubles as scratch (attn output, then FFN2 raw output).
  const u64 needBytes = (u64)(256 + 6 * NBSD) * sizeof(float);
  if (ws_size < needBytes) return;            // defensive: fail clean, not a fault

  float* Sc = (float*)d_ws;
  float* U0 = Sc + 256;
  float* U1 = U0 + NBSD;
  float* F  = U1 + NBSD;                      // 4*NBSD floats
  float* F0 = F;                              // temp k (pre-attention)
  float* F1 = F + NBSD;                       // temp v (pre-attention)

  // scale slots: 0:h1 1:Wq 2:Wk 3:Wv 4:Wo 5:W1 6:W2 7:o_proj 8:t(x2) 9:h2 10:gelu 11:final
  init_scalars<<<1, 64, 0, stream>>>(Sc);

  ln_kernel<<<Bdim * Sdim, 256, 0, stream>>>(x, g1, bn1, nullptr, U0, Sc + 0);

  absmax_kernel<<<512, 256, 0, stream>>>(Wq, (u64)Ddim * Ddim, Sc + 1);
  absmax_kernel<<<512, 256, 0, stream>>>(Wk, (u64)Ddim * Ddim, Sc + 2);
  absmax_kernel<<<512, 256, 0, stream>>>(Wv, (u64)Ddim * Ddim, Sc + 3);
  absmax_kernel<<<512, 256, 0, stream>>>(Wo, (u64)Ddim * Ddim, Sc + 4);
  absmax_kernel<<<2048, 256, 0, stream>>>(W1, (u64)4 * Ddim * Ddim, Sc + 5);
  absmax_kernel<<<2048, 256, 0, stream>>>(W2, (u64)4 * Ddim * Ddim, Sc + 6);

  dim3 gQKV(Ddim / 64, (Bdim * Sdim) / 64);   // (16,128)
  gemm_tn<<<gQKV, 256, 0, stream>>>(U0, Wq, bq, U1, Bdim * Sdim, Ddim, Ddim, Sc + 0, Sc + 1);
  gemm_tn<<<gQKV, 256, 0, stream>>>(U0, Wk, bk, F0, Bdim * Sdim, Ddim, Ddim, Sc + 0, Sc + 2);
  gemm_tn<<<gQKV, 256, 0, stream>>>(U0, Wv, bv, F1, Bdim * Sdim, Ddim, Ddim, Sc + 0, Sc + 3);

  rope_kernel<<<(Bdim * Sdim * Hdim * 32) / 256, 256, 0, stream>>>(U1, F0);

  dim3 gAttn(Sdim / 64, Bdim * Hdim);         // (32,64)
  attn_kernel<<<gAttn, 256, 0, stream>>>(U1, F0, F1, out);   // attn -> d_out (scratch)

  // o_proj: A (attention out) is NOT fake-quantized in the reference
  gemm_tn<<<gQKV, 256, 0, stream>>>(out, Wo, bo, U0, Bdim * Sdim, Ddim, Ddim, nullptr, Sc + 4);
  absmax_kernel<<<2048, 256, 0, stream>>>(U0, NBSD, Sc + 7);
  // t = fq(o_proj) + x   (x2 = fq(t) applied lazily by consumers via Sc+8)
  add_qdq_kernel<<<4096, 256, 0, stream>>>(U0, Sc + 7, x, U1, NBSD, Sc + 8);

  ln_kernel<<<Bdim * Sdim, 256, 0, stream>>>(U1, g2, bn2, Sc + 8, U0, Sc + 9);

  dim3 gW1(4 * Ddim / 64, (Bdim * Sdim) / 64);  // (64,128)
  gemm_tn<<<gW1, 256, 0, stream>>>(U0, W1, bf1, F, Bdim * Sdim, 4 * Ddim, Ddim, Sc + 9, Sc + 5);

  gelu_kernel<<<8192, 256, 0, stream>>>(F, 4 * NBSD, Sc + 10);

  gemm_tn<<<gQKV, 256, 0, stream>>>(F, W2, bf2, out, Bdim * Sdim, Ddim, 4 * Ddim, Sc + 10, Sc + 6);

  // u = ffn_raw + fq(t);  out = fq(u)
  final_add_kernel<<<4096, 256, 0, stream>>>(out, U1, Sc + 8, U0, NBSD, Sc + 11);
  qdq_out_kernel<<<4096, 256, 0, stream>>>(U0, Sc + 11, out, NBSD);
}

// Round 3
// 4832.251 us; speedup vs baseline: 1.8622x; 1.8622x over previous
//
#include <hip/hip_runtime.h>
#include <math.h>

#define Bdim 4
#define Sdim 2048
#define Ddim 1024
#define Hdim 16
#define HDdim 64

typedef unsigned long long u64;
typedef unsigned short ushort_t;
typedef int int4v __attribute__((ext_vector_type(4)));
typedef short short8v __attribute__((ext_vector_type(8)));
typedef float float4v __attribute__((ext_vector_type(4)));

// ---------------------------------------------------------------------------
// helpers
// ---------------------------------------------------------------------------
__device__ __forceinline__ float qdq_f(float x, float amax) {
  float s = fmaxf(amax / 127.0f, 1e-8f);
  float r = rintf(x / s);
  r = fminf(fmaxf(r, -128.0f), 127.0f);
  return r * s;
}

__device__ __forceinline__ void atomicMaxF(float* a, float v) {
  atomicMax((int*)a, __float_as_int(v));   // valid: non-negative floats
}

__device__ __forceinline__ float blockMax256(float v) {
  __shared__ float sred[4];
  #pragma unroll
  for (int o = 32; o > 0; o >>= 1) v = fmaxf(v, __shfl_xor(v, o));
  if ((threadIdx.x & 63) == 0) sred[threadIdx.x >> 6] = v;
  __syncthreads();
  return fmaxf(fmaxf(sred[0], sred[1]), fmaxf(sred[2], sred[3]));
}

__device__ __forceinline__ ushort_t f2bf(float f) {  // RNE fp32->bf16
  unsigned u = __float_as_uint(f);
  return (ushort_t)((u + 0x7FFFu + ((u >> 16) & 1u)) >> 16);
}

__global__ void init_scalars(float* s) { s[threadIdx.x] = 0.0f; }  // <<<1,64>>>

// ---------------------------------------------------------------------------
// absmax (grid-stride)
// ---------------------------------------------------------------------------
__global__ __launch_bounds__(256) void absmax_kernel(const float* __restrict__ x,
                                                     u64 n, float* __restrict__ amax) {
  u64 i = (u64)blockIdx.x * 256 + threadIdx.x;
  u64 stride = (u64)gridDim.x * 256;
  float m = 0.0f;
  for (; i < n; i += stride) m = fmaxf(m, fabsf(x[i]));
  m = blockMax256(m);
  if (threadIdx.x == 0) atomicMaxF(amax, m);
}

// ---------------------------------------------------------------------------
// quantize fp32 -> int8 (packed 4/thread)
// ---------------------------------------------------------------------------
__global__ __launch_bounds__(256) void quant8_kernel(
    const float* __restrict__ x, const float* __restrict__ amaxp,
    signed char* __restrict__ q, u64 n4)
{
  const float s = fmaxf(*amaxp / 127.0f, 1e-8f);
  u64 i = (u64)blockIdx.x * 256 + threadIdx.x;
  u64 stride = (u64)gridDim.x * 256;
  for (; i < n4; i += stride) {
    float4 v = ((const float4*)x)[i];
    int b0 = (int)fminf(fmaxf(rintf(v.x / s), -128.0f), 127.0f) & 255;
    int b1 = (int)fminf(fmaxf(rintf(v.y / s), -128.0f), 127.0f) & 255;
    int b2 = (int)fminf(fmaxf(rintf(v.z / s), -128.0f), 127.0f) & 255;
    int b3 = (int)fminf(fmaxf(rintf(v.w / s), -128.0f), 127.0f) & 255;
    ((unsigned*)q)[i] = (unsigned)(b0 | (b1 << 8) | (b2 << 16) | (b3 << 24));
  }
}

// quantize weight -> int stored as exact bf16 (|q|<=128 fits 8-bit mantissa)
__global__ __launch_bounds__(256) void quantbf_kernel(
    const float* __restrict__ w, const float* __restrict__ amaxp,
    ushort_t* __restrict__ o, u64 n)
{
  const float s = fmaxf(*amaxp / 127.0f, 1e-8f);
  u64 i = (u64)blockIdx.x * 256 + threadIdx.x;
  u64 stride = (u64)gridDim.x * 256;
  for (; i < n; i += stride) {
    float r = fminf(fmaxf(rintf(w[i] / s), -128.0f), 127.0f);
    o[i] = f2bf(r);
  }
}

// split fp32 -> bf16 hi + bf16 lo
__global__ __launch_bounds__(256) void split_bf16_kernel(
    const float* __restrict__ x, ushort_t* __restrict__ hi,
    ushort_t* __restrict__ lo, u64 n)
{
  u64 i = (u64)blockIdx.x * 256 + threadIdx.x;
  u64 stride = (u64)gridDim.x * 256;
  for (; i < n; i += stride) {
    float v = x[i];
    ushort_t h = f2bf(v);
    float hf = __uint_as_float(((unsigned)h) << 16);
    hi[i] = h;
    lo[i] = f2bf(v - hf);
  }
}

// ---------------------------------------------------------------------------
// LayerNorm (one block per row of 1024), optional input qdq, output absmax
// ---------------------------------------------------------------------------
__global__ __launch_bounds__(256) void ln_kernel(
    const float* __restrict__ x, const float* __restrict__ g,
    const float* __restrict__ beta, const float* __restrict__ inAmax,
    float* __restrict__ y, float* __restrict__ amaxOut)
{
  __shared__ float sred[4];
  __shared__ float smv[2];
  const int tid = threadIdx.x;
  const u64 row = blockIdx.x;
  const float* xr = x + row * Ddim;
  float* yr = y + row * Ddim;
  float aIn = inAmax ? *inAmax : 0.0f;

  float vals[4];
  float sum = 0.0f;
  #pragma unroll
  for (int i = 0; i < 4; i++) {
    float v = xr[tid + (i << 8)];
    if (inAmax) v = qdq_f(v, aIn);
    vals[i] = v;
    sum += v;
  }
  #pragma unroll
  for (int o = 32; o > 0; o >>= 1) sum += __shfl_xor(sum, o);
  if ((tid & 63) == 0) sred[tid >> 6] = sum;
  __syncthreads();
  if (tid == 0) smv[0] = (sred[0] + sred[1] + sred[2] + sred[3]) * (1.0f / 1024.0f);
  __syncthreads();
  const float mean = smv[0];

  float dev = 0.0f;
  #pragma unroll
  for (int i = 0; i < 4; i++) { float d = vals[i] - mean; dev += d * d; }
  #pragma unroll
  for (int o = 32; o > 0; o >>= 1) dev += __shfl_xor(dev, o);
  if ((tid & 63) == 0) sred[tid >> 6] = dev;
  __syncthreads();
  if (tid == 0) {
    float var = (sred[0] + sred[1] + sred[2] + sred[3]) * (1.0f / 1024.0f);
    smv[1] = 1.0f / sqrtf(var + 1e-5f);
  }
  __syncthreads();
  const float inv = smv[1];

  float lmax = 0.0f;
  #pragma unroll
  for (int i = 0; i < 4; i++) {
    int c = tid + (i << 8);
    float ov = (vals[i] - mean) * inv * g[c] + beta[c];
    yr[c] = ov;
    lmax = fmaxf(lmax, fabsf(ov));
  }
  #pragma unroll
  for (int o = 32; o > 0; o >>= 1) lmax = fmaxf(lmax, __shfl_xor(lmax, o));
  __syncthreads();
  if ((tid & 63) == 0) sred[tid >> 6] = lmax;
  __syncthreads();
  if (tid == 0)
    atomicMaxF(amaxOut, fmaxf(fmaxf(sred[0], sred[1]), fmaxf(sred[2], sred[3])));
}

// ---------------------------------------------------------------------------
// i8 MFMA GEMM: C[M,N] = (A8[M,K] @ B8[N,K]^T)*sA*sB + bias[N]
// 128x128 tile, BK=64, 2x2 waves x 4x4 mfma_i32_16x16x64_i8 tiles.
// EPI: 0 = none, 1 = gelu + amax tracking.
// LDS rows padded to 80 B -> 2-way bank aliasing (free).
// ---------------------------------------------------------------------------
template <int EPI>
__global__ __launch_bounds__(256) void gemm_i8(
    const signed char* __restrict__ A8, const signed char* __restrict__ B8,
    const float* __restrict__ bias, float* __restrict__ C,
    int M, int N, int K,
    const float* __restrict__ sAp, const float* __restrict__ sBp,
    float* __restrict__ amaxOut)
{
  __shared__ __align__(16) signed char As[128][80];
  __shared__ __align__(16) signed char Bs[128][80];
  const int tid = threadIdx.x;
  const int wave = tid >> 6, lane = tid & 63;
  const int quad = lane >> 4, l16 = lane & 15;
  const int wy = wave >> 1, wx = wave & 1;
  const int m0 = blockIdx.y << 7, n0 = blockIdx.x << 7;
  const float sA = fmaxf(*sAp / 127.0f, 1e-8f);
  const float sB = fmaxf(*sBp / 127.0f, 1e-8f);
  const float sAB = sA * sB;

  const int sr = tid >> 2;            // staging row 0..63
  const int sc = (tid & 3) << 4;      // staging byte col 0/16/32/48

  int4v acc[4][4] = {};
  for (int k0 = 0; k0 < K; k0 += 64) {
    #pragma unroll
    for (int p = 0; p < 2; p++) {
      int r = sr + (p << 6);
      uint4 av = *(const uint4*)&A8[(u64)(m0 + r) * K + k0 + sc];
      uint4 bv = *(const uint4*)&B8[(u64)(n0 + r) * K + k0 + sc];
      *(uint4*)&As[r][sc] = av;
      *(uint4*)&Bs[r][sc] = bv;
    }
    __syncthreads();
    int4v af[4], bf[4];
    #pragma unroll
    for (int mt = 0; mt < 4; mt++)
      af[mt] = *(const int4v*)&As[(wy << 6) + (mt << 4) + l16][quad << 4];
    #pragma unroll
    for (int nt = 0; nt < 4; nt++)
      bf[nt] = *(const int4v*)&Bs[(wx << 6) + (nt << 4) + l16][quad << 4];
    #pragma unroll
    for (int mt = 0; mt < 4; mt++)
      #pragma unroll
      for (int nt = 0; nt < 4; nt++)
        acc[mt][nt] = __builtin_amdgcn_mfma_i32_16x16x64_i8(af[mt], bf[nt], acc[mt][nt], 0, 0, 0);
    __syncthreads();
  }

  float lmax = 0.0f;
  #pragma unroll
  for (int mt = 0; mt < 4; mt++) {
    #pragma unroll
    for (int reg = 0; reg < 4; reg++) {
      int row = m0 + (wy << 6) + (mt << 4) + (quad << 2) + reg;
      #pragma unroll
      for (int nt = 0; nt < 4; nt++) {
        int col = n0 + (wx << 6) + (nt << 4) + l16;
        float v = (float)acc[mt][nt][reg] * sAB + bias[col];
        if (EPI == 1) {
          v = 0.5f * v * (1.0f + erff(v * 0.70710678118654752440f));
          lmax = fmaxf(lmax, fabsf(v));
        }
        C[(u64)row * N + col] = v;
      }
    }
  }
  if (EPI == 1) {
    lmax = blockMax256(lmax);
    if (tid == 0) atomicMaxF(amaxOut, lmax);
  }
}

// ---------------------------------------------------------------------------
// bf16-split MFMA GEMM for Wo: C = ((Ahi+Alo)[M,K] @ Wq[N,K]^T)*sW + bias
// fused output absmax. mfma_f32_16x16x32_bf16, BK=32.
// ---------------------------------------------------------------------------
__global__ __launch_bounds__(256) void gemm_bf16_wo(
    const ushort_t* __restrict__ Ahi, const ushort_t* __restrict__ Alo,
    const ushort_t* __restrict__ Bw, const float* __restrict__ bias,
    float* __restrict__ C, int M, int N, int K,
    const float* __restrict__ sWp, float* __restrict__ amaxOut)
{
  __shared__ __align__(16) ushort_t Hs[128][40];   // 32 elems + 8 pad = 80 B rows
  __shared__ __align__(16) ushort_t Ls[128][40];
  __shared__ __align__(16) ushort_t Ws[128][40];
  const int tid = threadIdx.x;
  const int wave = tid >> 6, lane = tid & 63;
  const int quad = lane >> 4, l16 = lane & 15;
  const int wy = wave >> 1, wx = wave & 1;
  const int m0 = blockIdx.y << 7, n0 = blockIdx.x << 7;
  const float sW = fmaxf(*sWp / 127.0f, 1e-8f);

  const int sr = tid >> 2;            // staging row 0..63
  const int sce = (tid & 3) << 3;     // staging element col 0/8/16/24

  float4v acc[4][4] = {};
  for (int k0 = 0; k0 < K; k0 += 32) {
    #pragma unroll
    for (int p = 0; p < 2; p++) {
      int r = sr + (p << 6);
      uint4 hv = *(const uint4*)&Ahi[(u64)(m0 + r) * K + k0 + sce];
      uint4 lv = *(const uint4*)&Alo[(u64)(m0 + r) * K + k0 + sce];
      uint4 wv = *(const uint4*)&Bw[(u64)(n0 + r) * K + k0 + sce];
      *(uint4*)&Hs[r][sce] = hv;
      *(uint4*)&Ls[r][sce] = lv;
      *(uint4*)&Ws[r][sce] = wv;
    }
    __syncthreads();
    short8v ah[4], al[4], bw[4];
    #pragma unroll
    for (int mt = 0; mt < 4; mt++) {
      ah[mt] = *(const short8v*)&Hs[(wy << 6) + (mt << 4) + l16][quad << 3];
      al[mt] = *(const short8v*)&Ls[(wy << 6) + (mt << 4) + l16][quad << 3];
    }
    #pragma unroll
    for (int nt = 0; nt < 4; nt++)
      bw[nt] = *(const short8v*)&Ws[(wx << 6) + (nt << 4) + l16][quad << 3];
    #pragma unroll
    for (int mt = 0; mt < 4; mt++)
      #pragma unroll
      for (int nt = 0; nt < 4; nt++) {
        acc[mt][nt] = __builtin_amdgcn_mfma_f32_16x16x32_bf16(ah[mt], bw[nt], acc[mt][nt], 0, 0, 0);
        acc[mt][nt] = __builtin_amdgcn_mfma_f32_16x16x32_bf16(al[mt], bw[nt], acc[mt][nt], 0, 0, 0);
      }
    __syncthreads();
  }

  float lmax = 0.0f;
  #pragma unroll
  for (int mt = 0; mt < 4; mt++) {
    #pragma unroll
    for (int reg = 0; reg < 4; reg++) {
      int row = m0 + (wy << 6) + (mt << 4) + (quad << 2) + reg;
      #pragma unroll
      for (int nt = 0; nt < 4; nt++) {
        int col = n0 + (wx << 6) + (nt << 4) + l16;
        float v = acc[mt][nt][reg] * sW + bias[col];
        lmax = fmaxf(lmax, fabsf(v));
        C[(u64)row * N + col] = v;
      }
    }
  }
  lmax = blockMax256(lmax);
  if (tid == 0) atomicMaxF(amaxOut, lmax);
}

// ---------------------------------------------------------------------------
// RoPE in-place on q and k, layout (B,S,H,HD); pair (i, i+32)
// ---------------------------------------------------------------------------
__global__ __launch_bounds__(256) void rope_kernel(float* __restrict__ q,
                                                   float* __restrict__ k) {
  u64 idx = (u64)blockIdx.x * 256 + threadIdx.x;  // B*S*H*32
  int i = (int)(idx & 31);
  int h = (int)((idx >> 5) & 15);
  int s = (int)((idx >> 9) & 2047);
  int b = (int)(idx >> 20);
  float inv = (float)pow(10000.0, -(double)i / 32.0);
  float ang = (float)s * inv;
  float cs = cosf(ang), sn = sinf(ang);
  u64 base = ((u64)(b * Sdim + s)) * Ddim + (u64)h * HDdim + i;
  float x1 = q[base], x2 = q[base + 32];
  q[base]      = x1 * cs - x2 * sn;
  q[base + 32] = x1 * sn + x2 * cs;
  x1 = k[base]; x2 = k[base + 32];
  k[base]      = x1 * cs - x2 * sn;
  k[base + 32] = x1 * sn + x2 * cs;
}

// ---------------------------------------------------------------------------
// Flash attention (fp32) — unchanged from round 2 (replaced next round)
// ---------------------------------------------------------------------------
__global__ __launch_bounds__(256) void attn_kernel(
    const float* __restrict__ Q, const float* __restrict__ K,
    const float* __restrict__ V, float* __restrict__ O)
{
  __shared__ __align__(16) float Qs[64][68];
  __shared__ __align__(16) float Ks[64][68];
  __shared__ __align__(16) float Vs[64][68];
  const int tid = threadIdx.x;
  const int b = blockIdx.y >> 4, h = blockIdx.y & 15;
  const int q0 = blockIdx.x << 6;
  const u64 baseBH = ((u64)b * Sdim) * Ddim + (u64)h * HDdim;

  #pragma unroll
  for (int i = 0; i < 16; i++) {
    int flat = tid + (i << 8);
    int r = flat >> 6, c = flat & 63;
    Qs[r][c] = Q[baseBH + (u64)(q0 + r) * Ddim + c];
  }

  const int rg = tid >> 4, cg = tid & 15;
  float m_run[4], l_run[4], oacc[4][4];
  #pragma unroll
  for (int i = 0; i < 4; i++) {
    m_run[i] = -INFINITY; l_run[i] = 0.0f;
    #pragma unroll
    for (int j = 0; j < 4; j++) oacc[i][j] = 0.0f;
  }

  for (int j0 = 0; j0 < Sdim; j0 += 64) {
    __syncthreads();
    #pragma unroll
    for (int i = 0; i < 16; i++) {
      int flat = tid + (i << 8);
      int r = flat >> 6, c = flat & 63;
      u64 gidx = baseBH + (u64)(j0 + r) * Ddim + c;
      Ks[r][c] = K[gidx];
      Vs[r][c] = V[gidx];
    }
    __syncthreads();

    float sc[4][4] = {};
    #pragma unroll
    for (int mm = 0; mm < 16; mm++) {
      int kk = ((mm + cg) & 15) << 2;
      float qa[4][4], ka[4][4];
      #pragma unroll
      for (int i = 0; i < 4; i++) {
        float4 t = *(const float4*)&Qs[(rg << 2) + i][kk];
        qa[i][0] = t.x; qa[i][1] = t.y; qa[i][2] = t.z; qa[i][3] = t.w;
      }
      #pragma unroll
      for (int j = 0; j < 4; j++) {
        float4 t = *(const float4*)&Ks[(cg << 2) + j][kk];
        ka[j][0] = t.x; ka[j][1] = t.y; ka[j][2] = t.z; ka[j][3] = t.w;
      }
      #pragma unroll
      for (int i = 0; i < 4; i++)
        #pragma unroll
        for (int j = 0; j < 4; j++)
          #pragma unroll
          for (int t = 0; t < 4; t++)
            sc[i][j] += qa[i][t] * ka[j][t];
    }

    float p[4][4], alpha[4];
    #pragma unroll
    for (int i = 0; i < 4; i++) {
      #pragma unroll
      for (int j = 0; j < 4; j++) sc[i][j] *= 0.125f;
      float mx = fmaxf(fmaxf(sc[i][0], sc[i][1]), fmaxf(sc[i][2], sc[i][3]));
      #pragma unroll
      for (int o = 8; o >= 1; o >>= 1) mx = fmaxf(mx, __shfl_xor(mx, o));
      float m_new = fmaxf(m_run[i], mx);
      alpha[i] = expf(m_run[i] - m_new);
      m_run[i] = m_new;
      float rs = 0.0f;
      #pragma unroll
      for (int j = 0; j < 4; j++) { p[i][j] = expf(sc[i][j] - m_new); rs += p[i][j]; }
      #pragma unroll
      for (int o = 8; o >= 1; o >>= 1) rs += __shfl_xor(rs, o);
      l_run[i] = l_run[i] * alpha[i] + rs;
    }

    __syncthreads();
    #pragma unroll
    for (int i = 0; i < 4; i++) {
      *(float4*)&Ks[(rg << 2) + i][cg << 2] =
          make_float4(p[i][0], p[i][1], p[i][2], p[i][3]);
      #pragma unroll
      for (int j = 0; j < 4; j++) oacc[i][j] *= alpha[i];
    }
    __syncthreads();

    #pragma unroll
    for (int t0 = 0; t0 < 64; t0 += 4) {
      float pa[4][4], va[4][4];
      #pragma unroll
      for (int i = 0; i < 4; i++) {
        float4 t = *(const float4*)&Ks[(rg << 2) + i][t0];
        pa[i][0] = t.x; pa[i][1] = t.y; pa[i][2] = t.z; pa[i][3] = t.w;
      }
      #pragma unroll
      for (int tt = 0; tt < 4; tt++) {
        float4 t = *(const float4*)&Vs[t0 + tt][cg << 2];
        va[tt][0] = t.x; va[tt][1] = t.y; va[tt][2] = t.z; va[tt][3] = t.w;
      }
      #pragma unroll
      for (int i = 0; i < 4; i++)
        #pragma unroll
        for (int j = 0; j < 4; j++)
          #pragma unroll
          for (int tt = 0; tt < 4; tt++)
            oacc[i][j] += pa[i][tt] * va[tt][j];
    }
  }

  #pragma unroll
  for (int i = 0; i < 4; i++) {
    float invl = 1.0f / l_run[i];
    *(float4*)&O[baseBH + (u64)(q0 + (rg << 2) + i) * Ddim + (cg << 2)] =
        make_float4(oacc[i][0] * invl, oacc[i][1] * invl,
                    oacc[i][2] * invl, oacc[i][3] * invl);
  }
}

// ---------------------------------------------------------------------------
// elementwise stages
// ---------------------------------------------------------------------------
__global__ __launch_bounds__(256) void add_qdq_kernel(
    const float* __restrict__ a, const float* __restrict__ amaxA,
    const float* __restrict__ x, float* __restrict__ outp, u64 n,
    float* __restrict__ amaxOut)
{
  const float aA = *amaxA;
  u64 i = (u64)blockIdx.x * 256 + threadIdx.x;
  u64 stride = (u64)gridDim.x * 256;
  float m = 0.0f;
  for (; i < n; i += stride) {
    float t = qdq_f(a[i], aA) + x[i];
    outp[i] = t;
    m = fmaxf(m, fabsf(t));
  }
  m = blockMax256(m);
  if (threadIdx.x == 0) atomicMaxF(amaxOut, m);
}

__global__ __launch_bounds__(256) void final_add_kernel(
    const float* __restrict__ hraw, const float* __restrict__ t,
    const float* __restrict__ amaxT, float* __restrict__ u, u64 n,
    float* __restrict__ amaxOut)
{
  const float aT = *amaxT;
  u64 i = (u64)blockIdx.x * 256 + threadIdx.x;
  u64 stride = (u64)gridDim.x * 256;
  float m = 0.0f;
  for (; i < n; i += stride) {
    float v = hraw[i] + qdq_f(t[i], aT);
    u[i] = v;
    m = fmaxf(m, fabsf(v));
  }
  m = blockMax256(m);
  if (threadIdx.x == 0) atomicMaxF(amaxOut, m);
}

__global__ __launch_bounds__(256) void qdq_out_kernel(
    const float* __restrict__ u, const float* __restrict__ amaxU,
    float* __restrict__ o, u64 n)
{
  const float aU = *amaxU;
  u64 i = (u64)blockIdx.x * 256 + threadIdx.x;
  u64 stride = (u64)gridDim.x * 256;
  for (; i < n; i += stride) o[i] = qdq_f(u[i], aU);
}

// ---------------------------------------------------------------------------
// launch
// ---------------------------------------------------------------------------
extern "C" void kernel_launch(void* const* d_in, const int* in_sizes, int n_in,
                              void* d_out, int out_size, void* d_ws, size_t ws_size,
                              hipStream_t stream)
{
  const float* x   = (const float*)d_in[0];
  const float* g1  = (const float*)d_in[1];
  const float* bn1 = (const float*)d_in[2];
  const float* Wq  = (const float*)d_in[3];
  const float* bq  = (const float*)d_in[4];
  const float* Wk  = (const float*)d_in[5];
  const float* bk  = (const float*)d_in[6];
  const float* Wv  = (const float*)d_in[7];
  const float* bv  = (const float*)d_in[8];
  const float* Wo  = (const float*)d_in[9];
  const float* bo  = (const float*)d_in[10];
  const float* g2  = (const float*)d_in[11];
  const float* bn2 = (const float*)d_in[12];
  const float* W1  = (const float*)d_in[13];
  const float* bf1 = (const float*)d_in[14];
  const float* W2  = (const float*)d_in[15];
  const float* bf2 = (const float*)d_in[16];
  float* out = (float*)d_out;

  const u64 NBSD = (u64)Bdim * Sdim * Ddim;     // 8,388,608
  const u64 NB4  = NBSD * 4;                    // bytes of one fp32 act buffer
  const u64 DD   = (u64)Ddim * Ddim;            // 1,048,576

  // ws layout (245 MiB total):
  // [Sc 1KiB][U0 NB4][U1 NB4][F 4*NB4][A8][Wq8][Wk8][Wv8][W18][W28][WoBF][OHI][OLO]
  char* Wb = (char*)d_ws;
  float*       Sc   = (float*)Wb;
  float*       U0   = (float*)(Wb + 1024);
  float*       U1   = (float*)(Wb + 1024 + NB4);
  float*       F    = (float*)(Wb + 1024 + 2 * NB4);
  signed char* A8   = (signed char*)(Wb + 1024 + 6 * NB4);
  signed char* Wq8  = A8 + NBSD;
  signed char* Wk8  = Wq8 + DD;
  signed char* Wv8  = Wk8 + DD;
  signed char* W18  = Wv8 + DD;
  signed char* W28  = W18 + 4 * DD;
  ushort_t*    WoBF = (ushort_t*)(W28 + 4 * DD);
  ushort_t*    OHI  = WoBF + DD;
  ushort_t*    OLO  = OHI + NBSD;
  signed char* G8   = (signed char*)U0;          // aliases U0 (dead by then)
  float* F0 = F;                                  // temp k (pre-attention)
  float* F1 = F + NBSD;                           // temp v (pre-attention)

  const u64 needBytes = (u64)((char*)(OLO + NBSD) - Wb);
  if (ws_size < needBytes) return;               // fail clean, not a fault

  // scales: 0:h1 1:Wq 2:Wk 3:Wv 4:Wo 5:W1 6:W2 7:o_proj 8:t 9:h2 10:gelu 11:final
  init_scalars<<<1, 64, 0, stream>>>(Sc);

  ln_kernel<<<Bdim * Sdim, 256, 0, stream>>>(x, g1, bn1, nullptr, U0, Sc + 0);

  absmax_kernel<<<512, 256, 0, stream>>>(Wq, DD, Sc + 1);
  absmax_kernel<<<512, 256, 0, stream>>>(Wk, DD, Sc + 2);
  absmax_kernel<<<512, 256, 0, stream>>>(Wv, DD, Sc + 3);
  absmax_kernel<<<512, 256, 0, stream>>>(Wo, DD, Sc + 4);
  absmax_kernel<<<2048, 256, 0, stream>>>(W1, 4 * DD, Sc + 5);
  absmax_kernel<<<2048, 256, 0, stream>>>(W2, 4 * DD, Sc + 6);

  // quantize activations + weights to int8 (exact-representation path)
  quant8_kernel<<<4096, 256, 0, stream>>>(U0, Sc + 0, A8, NBSD / 4);
  quant8_kernel<<<1024, 256, 0, stream>>>(Wq, Sc + 1, Wq8, DD / 4);
  quant8_kernel<<<1024, 256, 0, stream>>>(Wk, Sc + 2, Wk8, DD / 4);
  quant8_kernel<<<1024, 256, 0, stream>>>(Wv, Sc + 3, Wv8, DD / 4);
  quant8_kernel<<<4096, 256, 0, stream>>>(W1, Sc + 5, W18, DD);       // 4*DD/4
  quant8_kernel<<<4096, 256, 0, stream>>>(W2, Sc + 6, W28, DD);
  quantbf_kernel<<<2048, 256, 0, stream>>>(Wo, Sc + 4, WoBF, DD);

  const int M = Bdim * Sdim;                     // 8192
  dim3 gP(Ddim / 128, M / 128);                  // (8, 64)
  gemm_i8<0><<<gP, 256, 0, stream>>>(A8, Wq8, bq, U1, M, Ddim, Ddim, Sc + 0, Sc + 1, nullptr);
  gemm_i8<0><<<gP, 256, 0, stream>>>(A8, Wk8, bk, F0, M, Ddim, Ddim, Sc + 0, Sc + 2, nullptr);
  gemm_i8<0><<<gP, 256, 0, stream>>>(A8, Wv8, bv, F1, M, Ddim, Ddim, Sc + 0, Sc + 3, nullptr);

  rope_kernel<<<(Bdim * Sdim * Hdim * 32) / 256, 256, 0, stream>>>(U1, F0);

  dim3 gAttn(Sdim / 64, Bdim * Hdim);            // (32, 64)
  attn_kernel<<<gAttn, 256, 0, stream>>>(U1, F0, F1, out);   // attn -> d_out

  // Wo projection: o (unquantized) via bf16 hi/lo split, W as int-in-bf16
  split_bf16_kernel<<<4096, 256, 0, stream>>>(out, OHI, OLO, NBSD);
  gemm_bf16_wo<<<gP, 256, 0, stream>>>(OHI, OLO, WoBF, bo, U0, M, Ddim, Ddim, Sc + 4, Sc + 7);

  add_qdq_kernel<<<4096, 256, 0, stream>>>(U0, Sc + 7, x, U1, NBSD, Sc + 8);

  ln_kernel<<<Bdim * Sdim, 256, 0, stream>>>(U1, g2, bn2, Sc + 8, U0, Sc + 9);
  quant8_kernel<<<4096, 256, 0, stream>>>(U0, Sc + 9, A8, NBSD / 4);

  dim3 gF1(4 * Ddim / 128, M / 128);             // (32, 64)
  gemm_i8<1><<<gF1, 256, 0, stream>>>(A8, W18, bf1, F, M, 4 * Ddim, Ddim, Sc + 9, Sc + 5, Sc + 10);

  quant8_kernel<<<4096, 256, 0, stream>>>(F, Sc + 10, G8, NBSD);      // 4*NBSD/4

  gemm_i8<0><<<gP, 256, 0, stream>>>(G8, W28, bf2, out, M, Ddim, 4 * Ddim, Sc + 10, Sc + 6, nullptr);

  final_add_kernel<<<4096, 256, 0, stream>>>(out, U1, Sc + 8, U0, NBSD, Sc + 11);
  qdq_out_kernel<<<4096, 256, 0, stream>>>(U0, Sc + 11, out, NBSD);
}

// Round 4
// 1615.769 us; speedup vs baseline: 5.5691x; 2.9907x over previous
//
#include <hip/hip_runtime.h>
#include <math.h>

#define Bdim 4
#define Sdim 2048
#define Ddim 1024
#define Hdim 16
#define HDdim 64

typedef unsigned long long u64;
typedef unsigned short ushort_t;
typedef int int4v __attribute__((ext_vector_type(4)));
typedef short short8v __attribute__((ext_vector_type(8)));
typedef float float4v __attribute__((ext_vector_type(4)));
typedef unsigned short us4v __attribute__((ext_vector_type(4)));

// ---------------------------------------------------------------------------
// helpers
// ---------------------------------------------------------------------------
__device__ __forceinline__ float qdq_f(float x, float amax) {
  float s = fmaxf(amax / 127.0f, 1e-8f);
  float r = rintf(x / s);
  r = fminf(fmaxf(r, -128.0f), 127.0f);
  return r * s;
}

__device__ __forceinline__ void atomicMaxF(float* a, float v) {
  atomicMax((int*)a, __float_as_int(v));   // valid: non-negative floats
}

__device__ __forceinline__ float blockMax256(float v) {
  __shared__ float sred[4];
  #pragma unroll
  for (int o = 32; o > 0; o >>= 1) v = fmaxf(v, __shfl_xor(v, o));
  if ((threadIdx.x & 63) == 0) sred[threadIdx.x >> 6] = v;
  __syncthreads();
  return fmaxf(fmaxf(sred[0], sred[1]), fmaxf(sred[2], sred[3]));
}

__device__ __forceinline__ ushort_t f2bf(float f) {  // RNE fp32->bf16
  unsigned u = __float_as_uint(f);
  return (ushort_t)((u + 0x7FFFu + ((u >> 16) & 1u)) >> 16);
}
__device__ __forceinline__ float bf2f(ushort_t h) {
  return __uint_as_float(((unsigned)h) << 16);
}

__global__ void init_scalars(float* s) { s[threadIdx.x] = 0.0f; }  // <<<1,64>>>

// ---------------------------------------------------------------------------
// absmax (grid-stride)
// ---------------------------------------------------------------------------
__global__ __launch_bounds__(256) void absmax_kernel(const float* __restrict__ x,
                                                     u64 n, float* __restrict__ amax) {
  u64 i = (u64)blockIdx.x * 256 + threadIdx.x;
  u64 stride = (u64)gridDim.x * 256;
  float m = 0.0f;
  for (; i < n; i += stride) m = fmaxf(m, fabsf(x[i]));
  m = blockMax256(m);
  if (threadIdx.x == 0) atomicMaxF(amax, m);
}

// ---------------------------------------------------------------------------
// quantize fp32 -> int8 (packed 4/thread)
// ---------------------------------------------------------------------------
__global__ __launch_bounds__(256) void quant8_kernel(
    const float* __restrict__ x, const float* __restrict__ amaxp,
    signed char* __restrict__ q, u64 n4)
{
  const float s = fmaxf(*amaxp / 127.0f, 1e-8f);
  u64 i = (u64)blockIdx.x * 256 + threadIdx.x;
  u64 stride = (u64)gridDim.x * 256;
  for (; i < n4; i += stride) {
    float4 v = ((const float4*)x)[i];
    int b0 = (int)fminf(fmaxf(rintf(v.x / s), -128.0f), 127.0f) & 255;
    int b1 = (int)fminf(fmaxf(rintf(v.y / s), -128.0f), 127.0f) & 255;
    int b2 = (int)fminf(fmaxf(rintf(v.z / s), -128.0f), 127.0f) & 255;
    int b3 = (int)fminf(fmaxf(rintf(v.w / s), -128.0f), 127.0f) & 255;
    ((unsigned*)q)[i] = (unsigned)(b0 | (b1 << 8) | (b2 << 16) | (b3 << 24));
  }
}

// quantize weight -> int stored as exact bf16 (|q|<=128 fits 8-bit mantissa)
__global__ __launch_bounds__(256) void quantbf_kernel(
    const float* __restrict__ w, const float* __restrict__ amaxp,
    ushort_t* __restrict__ o, u64 n)
{
  const float s = fmaxf(*amaxp / 127.0f, 1e-8f);
  u64 i = (u64)blockIdx.x * 256 + threadIdx.x;
  u64 stride = (u64)gridDim.x * 256;
  for (; i < n; i += stride) {
    float r = fminf(fmaxf(rintf(w[i] / s), -128.0f), 127.0f);
    o[i] = f2bf(r);
  }
}

// split fp32 -> bf16 hi + bf16 lo
__global__ __launch_bounds__(256) void split_bf16_kernel(
    const float* __restrict__ x, ushort_t* __restrict__ hi,
    ushort_t* __restrict__ lo, u64 n)
{
  u64 i = (u64)blockIdx.x * 256 + threadIdx.x;
  u64 stride = (u64)gridDim.x * 256;
  for (; i < n; i += stride) {
    float v = x[i];
    ushort_t h = f2bf(v);
    hi[i] = h;
    lo[i] = f2bf(v - bf2f(h));
  }
}

// ---------------------------------------------------------------------------
// LayerNorm (one block per row of 1024), optional input qdq, output absmax
// ---------------------------------------------------------------------------
__global__ __launch_bounds__(256) void ln_kernel(
    const float* __restrict__ x, const float* __restrict__ g,
    const float* __restrict__ beta, const float* __restrict__ inAmax,
    float* __restrict__ y, float* __restrict__ amaxOut)
{
  __shared__ float sred[4];
  __shared__ float smv[2];
  const int tid = threadIdx.x;
  const u64 row = blockIdx.x;
  const float* xr = x + row * Ddim;
  float* yr = y + row * Ddim;
  float aIn = inAmax ? *inAmax : 0.0f;

  float vals[4];
  float sum = 0.0f;
  #pragma unroll
  for (int i = 0; i < 4; i++) {
    float v = xr[tid + (i << 8)];
    if (inAmax) v = qdq_f(v, aIn);
    vals[i] = v;
    sum += v;
  }
  #pragma unroll
  for (int o = 32; o > 0; o >>= 1) sum += __shfl_xor(sum, o);
  if ((tid & 63) == 0) sred[tid >> 6] = sum;
  __syncthreads();
  if (tid == 0) smv[0] = (sred[0] + sred[1] + sred[2] + sred[3]) * (1.0f / 1024.0f);
  __syncthreads();
  const float mean = smv[0];

  float dev = 0.0f;
  #pragma unroll
  for (int i = 0; i < 4; i++) { float d = vals[i] - mean; dev += d * d; }
  #pragma unroll
  for (int o = 32; o > 0; o >>= 1) dev += __shfl_xor(dev, o);
  if ((tid & 63) == 0) sred[tid >> 6] = dev;
  __syncthreads();
  if (tid == 0) {
    float var = (sred[0] + sred[1] + sred[2] + sred[3]) * (1.0f / 1024.0f);
    smv[1] = 1.0f / sqrtf(var + 1e-5f);
  }
  __syncthreads();
  const float inv = smv[1];

  float lmax = 0.0f;
  #pragma unroll
  for (int i = 0; i < 4; i++) {
    int c = tid + (i << 8);
    float ov = (vals[i] - mean) * inv * g[c] + beta[c];
    yr[c] = ov;
    lmax = fmaxf(lmax, fabsf(ov));
  }
  #pragma unroll
  for (int o = 32; o > 0; o >>= 1) lmax = fmaxf(lmax, __shfl_xor(lmax, o));
  __syncthreads();
  if ((tid & 63) == 0) sred[tid >> 6] = lmax;
  __syncthreads();
  if (tid == 0)
    atomicMaxF(amaxOut, fmaxf(fmaxf(sred[0], sred[1]), fmaxf(sred[2], sred[3])));
}

// ---------------------------------------------------------------------------
// i8 MFMA GEMM: C[M,N] = (A8[M,K] @ B8[N,K]^T)*sA*sB + bias[N]
// 128x128 tile, BK=64, 2x2 waves x 4x4 mfma_i32_16x16x64_i8 tiles.
// EPI: 0 = none, 1 = gelu + amax tracking.
// ---------------------------------------------------------------------------
template <int EPI>
__global__ __launch_bounds__(256) void gemm_i8(
    const signed char* __restrict__ A8, const signed char* __restrict__ B8,
    const float* __restrict__ bias, float* __restrict__ C,
    int M, int N, int K,
    const float* __restrict__ sAp, const float* __restrict__ sBp,
    float* __restrict__ amaxOut)
{
  __shared__ __align__(16) signed char As[128][80];
  __shared__ __align__(16) signed char Bs[128][80];
  const int tid = threadIdx.x;
  const int wave = tid >> 6, lane = tid & 63;
  const int quad = lane >> 4, l16 = lane & 15;
  const int wy = wave >> 1, wx = wave & 1;
  const int m0 = blockIdx.y << 7, n0 = blockIdx.x << 7;
  const float sA = fmaxf(*sAp / 127.0f, 1e-8f);
  const float sB = fmaxf(*sBp / 127.0f, 1e-8f);
  const float sAB = sA * sB;

  const int sr = tid >> 2;            // staging row 0..63
  const int sc = (tid & 3) << 4;      // staging byte col 0/16/32/48

  int4v acc[4][4] = {};
  for (int k0 = 0; k0 < K; k0 += 64) {
    #pragma unroll
    for (int p = 0; p < 2; p++) {
      int r = sr + (p << 6);
      uint4 av = *(const uint4*)&A8[(u64)(m0 + r) * K + k0 + sc];
      uint4 bv = *(const uint4*)&B8[(u64)(n0 + r) * K + k0 + sc];
      *(uint4*)&As[r][sc] = av;
      *(uint4*)&Bs[r][sc] = bv;
    }
    __syncthreads();
    int4v af[4], bf[4];
    #pragma unroll
    for (int mt = 0; mt < 4; mt++)
      af[mt] = *(const int4v*)&As[(wy << 6) + (mt << 4) + l16][quad << 4];
    #pragma unroll
    for (int nt = 0; nt < 4; nt++)
      bf[nt] = *(const int4v*)&Bs[(wx << 6) + (nt << 4) + l16][quad << 4];
    #pragma unroll
    for (int mt = 0; mt < 4; mt++)
      #pragma unroll
      for (int nt = 0; nt < 4; nt++)
        acc[mt][nt] = __builtin_amdgcn_mfma_i32_16x16x64_i8(af[mt], bf[nt], acc[mt][nt], 0, 0, 0);
    __syncthreads();
  }

  float lmax = 0.0f;
  #pragma unroll
  for (int mt = 0; mt < 4; mt++) {
    #pragma unroll
    for (int reg = 0; reg < 4; reg++) {
      int row = m0 + (wy << 6) + (mt << 4) + (quad << 2) + reg;
      #pragma unroll
      for (int nt = 0; nt < 4; nt++) {
        int col = n0 + (wx << 6) + (nt << 4) + l16;
        float v = (float)acc[mt][nt][reg] * sAB + bias[col];
        if (EPI == 1) {
          v = 0.5f * v * (1.0f + erff(v * 0.70710678118654752440f));
          lmax = fmaxf(lmax, fabsf(v));
        }
        C[(u64)row * N + col] = v;
      }
    }
  }
  if (EPI == 1) {
    lmax = blockMax256(lmax);
    if (tid == 0) atomicMaxF(amaxOut, lmax);
  }
}

// ---------------------------------------------------------------------------
// bf16-split MFMA GEMM for Wo: C = ((Ahi+Alo)[M,K] @ Wq[N,K]^T)*sW + bias
// fused output absmax. mfma_f32_16x16x32_bf16, BK=32.
// ---------------------------------------------------------------------------
__global__ __launch_bounds__(256) void gemm_bf16_wo(
    const ushort_t* __restrict__ Ahi, const ushort_t* __restrict__ Alo,
    const ushort_t* __restrict__ Bw, const float* __restrict__ bias,
    float* __restrict__ C, int M, int N, int K,
    const float* __restrict__ sWp, float* __restrict__ amaxOut)
{
  __shared__ __align__(16) ushort_t Hs[128][40];
  __shared__ __align__(16) ushort_t Ls[128][40];
  __shared__ __align__(16) ushort_t Ws[128][40];
  const int tid = threadIdx.x;
  const int wave = tid >> 6, lane = tid & 63;
  const int quad = lane >> 4, l16 = lane & 15;
  const int wy = wave >> 1, wx = wave & 1;
  const int m0 = blockIdx.y << 7, n0 = blockIdx.x << 7;
  const float sW = fmaxf(*sWp / 127.0f, 1e-8f);

  const int sr = tid >> 2;
  const int sce = (tid & 3) << 3;

  float4v acc[4][4] = {};
  for (int k0 = 0; k0 < K; k0 += 32) {
    #pragma unroll
    for (int p = 0; p < 2; p++) {
      int r = sr + (p << 6);
      uint4 hv = *(const uint4*)&Ahi[(u64)(m0 + r) * K + k0 + sce];
      uint4 lv = *(const uint4*)&Alo[(u64)(m0 + r) * K + k0 + sce];
      uint4 wv = *(const uint4*)&Bw[(u64)(n0 + r) * K + k0 + sce];
      *(uint4*)&Hs[r][sce] = hv;
      *(uint4*)&Ls[r][sce] = lv;
      *(uint4*)&Ws[r][sce] = wv;
    }
    __syncthreads();
    short8v ah[4], al[4], bw[4];
    #pragma unroll
    for (int mt = 0; mt < 4; mt++) {
      ah[mt] = *(const short8v*)&Hs[(wy << 6) + (mt << 4) + l16][quad << 3];
      al[mt] = *(const short8v*)&Ls[(wy << 6) + (mt << 4) + l16][quad << 3];
    }
    #pragma unroll
    for (int nt = 0; nt < 4; nt++)
      bw[nt] = *(const short8v*)&Ws[(wx << 6) + (nt << 4) + l16][quad << 3];
    #pragma unroll
    for (int mt = 0; mt < 4; mt++)
      #pragma unroll
      for (int nt = 0; nt < 4; nt++) {
        acc[mt][nt] = __builtin_amdgcn_mfma_f32_16x16x32_bf16(ah[mt], bw[nt], acc[mt][nt], 0, 0, 0);
        acc[mt][nt] = __builtin_amdgcn_mfma_f32_16x16x32_bf16(al[mt], bw[nt], acc[mt][nt], 0, 0, 0);
      }
    __syncthreads();
  }

  float lmax = 0.0f;
  #pragma unroll
  for (int mt = 0; mt < 4; mt++) {
    #pragma unroll
    for (int reg = 0; reg < 4; reg++) {
      int row = m0 + (wy << 6) + (mt << 4) + (quad << 2) + reg;
      #pragma unroll
      for (int nt = 0; nt < 4; nt++) {
        int col = n0 + (wx << 6) + (nt << 4) + l16;
        float v = acc[mt][nt][reg] * sW + bias[col];
        lmax = fmaxf(lmax, fabsf(v));
        C[(u64)row * N + col] = v;
      }
    }
  }
  lmax = blockMax256(lmax);
  if (tid == 0) atomicMaxF(amaxOut, lmax);
}

// ---------------------------------------------------------------------------
// RoPE in-place on q and k, layout (B,S,H,HD); pair (i, i+32)
// ---------------------------------------------------------------------------
__global__ __launch_bounds__(256) void rope_kernel(float* __restrict__ q,
                                                   float* __restrict__ k) {
  u64 idx = (u64)blockIdx.x * 256 + threadIdx.x;  // B*S*H*32
  int i = (int)(idx & 31);
  int h = (int)((idx >> 5) & 15);
  int s = (int)((idx >> 9) & 2047);
  int b = (int)(idx >> 20);
  float inv = powf(10000.0f, -(float)i * (1.0f / 32.0f));
  float ang = (float)s * inv;
  float cs = cosf(ang), sn = sinf(ang);
  u64 base = ((u64)(b * Sdim + s)) * Ddim + (u64)h * HDdim + i;
  float x1 = q[base], x2 = q[base + 32];
  q[base]      = x1 * cs - x2 * sn;
  q[base + 32] = x1 * sn + x2 * cs;
  x1 = k[base]; x2 = k[base + 32];
  k[base]      = x1 * cs - x2 * sn;
  k[base + 32] = x1 * sn + x2 * cs;
}

// ---------------------------------------------------------------------------
// MFMA flash attention, fp32-equivalent via bf16 hi/lo splits.
// Block = (b,h, 64 q-rows), 4 waves x 16 rows. KV tile 64.
// QK^T and PV each use 3 mfma_f32_16x16x32_bf16 per k-chunk (hi*hi+hi*lo+lo*hi).
// P overwrites K's LDS (KP arrays) after a barrier. LDS = 6*9216 = 54KB.
// Verified layouts (same as passing GEMMs): A[m=l16][k=quad*8+j];
// C/D: col=l16, row=quad*4+reg.
// ---------------------------------------------------------------------------
__global__ __launch_bounds__(256) void attn_kernel(
    const float* __restrict__ Q, const float* __restrict__ K,
    const float* __restrict__ V, float* __restrict__ O)
{
  __shared__ __align__(16) ushort_t Qhi[64][72], Qlo[64][72];
  __shared__ __align__(16) ushort_t KPhi[64][72], KPlo[64][72];  // K tile, then P
  __shared__ __align__(16) ushort_t Vthi[64][72], Vtlo[64][72];  // V transposed [hd][kv]
  const int tid = threadIdx.x;
  const int wave = tid >> 6, lane = tid & 63;
  const int quad = lane >> 4, l16 = lane & 15;
  const int w16 = wave << 4;                 // this wave's q-row base (16 rows)
  const int b = blockIdx.y >> 4, h = blockIdx.y & 15;
  const int q0 = blockIdx.x << 6;
  const u64 baseBH = ((u64)b * Sdim) * Ddim + (u64)h * HDdim;

  // ---- stage Q tile (hi/lo split) ----
  #pragma unroll
  for (int i = 0; i < 4; i++) {
    int idx = tid + (i << 8);                // 0..1023
    int r = idx >> 4, c4 = (idx & 15) << 2;
    float4 v = *(const float4*)&Q[baseBH + (u64)(q0 + r) * Ddim + c4];
    ushort_t h0 = f2bf(v.x), h1 = f2bf(v.y), h2 = f2bf(v.z), h3 = f2bf(v.w);
    *(us4v*)&Qhi[r][c4] = (us4v){h0, h1, h2, h3};
    *(us4v*)&Qlo[r][c4] = (us4v){f2bf(v.x - bf2f(h0)), f2bf(v.y - bf2f(h1)),
                                 f2bf(v.z - bf2f(h2)), f2bf(v.w - bf2f(h3))};
  }

  float4v oacc[4] = {};
  float m_run[4], l_run[4];
  #pragma unroll
  for (int r = 0; r < 4; r++) { m_run[r] = -INFINITY; l_run[r] = 0.0f; }

  for (int j0 = 0; j0 < Sdim; j0 += 64) {
    __syncthreads();                         // prev iter's LDS reads done
    // ---- stage K (hi/lo) and V (transposed hi/lo) ----
    #pragma unroll
    for (int i = 0; i < 4; i++) {
      int idx = tid + (i << 8);
      int r = idx >> 4, c4 = (idx & 15) << 2;
      u64 gidx = baseBH + (u64)(j0 + r) * Ddim + c4;
      float4 kv = *(const float4*)&K[gidx];
      ushort_t h0 = f2bf(kv.x), h1 = f2bf(kv.y), h2 = f2bf(kv.z), h3 = f2bf(kv.w);
      *(us4v*)&KPhi[r][c4] = (us4v){h0, h1, h2, h3};
      *(us4v*)&KPlo[r][c4] = (us4v){f2bf(kv.x - bf2f(h0)), f2bf(kv.y - bf2f(h1)),
                                    f2bf(kv.z - bf2f(h2)), f2bf(kv.w - bf2f(h3))};
      float4 vv = *(const float4*)&V[gidx];
      float va[4] = {vv.x, vv.y, vv.z, vv.w};
      #pragma unroll
      for (int k = 0; k < 4; k++) {
        ushort_t vh = f2bf(va[k]);
        Vthi[c4 + k][r] = vh;
        Vtlo[c4 + k][r] = f2bf(va[k] - bf2f(vh));
      }
    }
    __syncthreads();

    // ---- scores = Q K^T (3-term hi/lo) ----
    float4v sc[4] = {};
    #pragma unroll
    for (int kk = 0; kk < 64; kk += 32) {
      short8v ahi = *(const short8v*)&Qhi[w16 + l16][kk + (quad << 3)];
      short8v alo = *(const short8v*)&Qlo[w16 + l16][kk + (quad << 3)];
      #pragma unroll
      for (int nt = 0; nt < 4; nt++) {
        short8v bhi = *(const short8v*)&KPhi[(nt << 4) + l16][kk + (quad << 3)];
        short8v blo = *(const short8v*)&KPlo[(nt << 4) + l16][kk + (quad << 3)];
        sc[nt] = __builtin_amdgcn_mfma_f32_16x16x32_bf16(ahi, bhi, sc[nt], 0, 0, 0);
        sc[nt] = __builtin_amdgcn_mfma_f32_16x16x32_bf16(ahi, blo, sc[nt], 0, 0, 0);
        sc[nt] = __builtin_amdgcn_mfma_f32_16x16x32_bf16(alo, bhi, sc[nt], 0, 0, 0);
      }
    }

    // ---- online softmax (per C/D row = quad*4+reg; cols on l16 lanes) ----
    float p[4][4], alpha[4];
    #pragma unroll
    for (int r = 0; r < 4; r++) {
      float s0 = sc[0][r] * 0.125f, s1 = sc[1][r] * 0.125f;
      float s2 = sc[2][r] * 0.125f, s3 = sc[3][r] * 0.125f;
      float mx = fmaxf(fmaxf(s0, s1), fmaxf(s2, s3));
      #pragma unroll
      for (int o = 8; o >= 1; o >>= 1) mx = fmaxf(mx, __shfl_xor(mx, o));
      float m_new = fmaxf(m_run[r], mx);
      alpha[r] = expf(m_run[r] - m_new);
      m_run[r] = m_new;
      p[0][r] = expf(s0 - m_new); p[1][r] = expf(s1 - m_new);
      p[2][r] = expf(s2 - m_new); p[3][r] = expf(s3 - m_new);
      float rs = p[0][r] + p[1][r] + p[2][r] + p[3][r];
      #pragma unroll
      for (int o = 8; o >= 1; o >>= 1) rs += __shfl_xor(rs, o);
      l_run[r] = l_run[r] * alpha[r] + rs;
    }

    __syncthreads();                         // all K-frag reads done
    // ---- write P (hi/lo) into KP arrays; rescale O ----
    #pragma unroll
    for (int nt = 0; nt < 4; nt++)
      #pragma unroll
      for (int r = 0; r < 4; r++) {
        float pv = p[nt][r];
        ushort_t ph = f2bf(pv);
        KPhi[w16 + (quad << 2) + r][(nt << 4) + l16] = ph;
        KPlo[w16 + (quad << 2) + r][(nt << 4) + l16] = f2bf(pv - bf2f(ph));
      }
    #pragma unroll
    for (int nt2 = 0; nt2 < 4; nt2++)
      #pragma unroll
      for (int r = 0; r < 4; r++) oacc[nt2][r] *= alpha[r];
    __syncthreads();                         // P visible

    // ---- O += P V (3-term hi/lo) ----
    #pragma unroll
    for (int kk = 0; kk < 64; kk += 32) {
      short8v phi = *(const short8v*)&KPhi[w16 + l16][kk + (quad << 3)];
      short8v plo = *(const short8v*)&KPlo[w16 + l16][kk + (quad << 3)];
      #pragma unroll
      for (int nt2 = 0; nt2 < 4; nt2++) {
        short8v vhi = *(const short8v*)&Vthi[(nt2 << 4) + l16][kk + (quad << 3)];
        short8v vlo = *(const short8v*)&Vtlo[(nt2 << 4) + l16][kk + (quad << 3)];
        oacc[nt2] = __builtin_amdgcn_mfma_f32_16x16x32_bf16(phi, vhi, oacc[nt2], 0, 0, 0);
        oacc[nt2] = __builtin_amdgcn_mfma_f32_16x16x32_bf16(phi, vlo, oacc[nt2], 0, 0, 0);
        oacc[nt2] = __builtin_amdgcn_mfma_f32_16x16x32_bf16(plo, vhi, oacc[nt2], 0, 0, 0);
      }
    }
  }

  // ---- epilogue: O / l ----
  #pragma unroll
  for (int r = 0; r < 4; r++) {
    float invl = 1.0f / l_run[r];
    #pragma unroll
    for (int nt2 = 0; nt2 < 4; nt2++)
      O[baseBH + (u64)(q0 + w16 + (quad << 2) + r) * Ddim + (nt2 << 4) + l16] =
          oacc[nt2][r] * invl;
  }
}

// ---------------------------------------------------------------------------
// elementwise stages
// ---------------------------------------------------------------------------
__global__ __launch_bounds__(256) void add_qdq_kernel(
    const float* __restrict__ a, const float* __restrict__ amaxA,
    const float* __restrict__ x, float* __restrict__ outp, u64 n,
    float* __restrict__ amaxOut)
{
  const float aA = *amaxA;
  u64 i = (u64)blockIdx.x * 256 + threadIdx.x;
  u64 stride = (u64)gridDim.x * 256;
  float m = 0.0f;
  for (; i < n; i += stride) {
    float t = qdq_f(a[i], aA) + x[i];
    outp[i] = t;
    m = fmaxf(m, fabsf(t));
  }
  m = blockMax256(m);
  if (threadIdx.x == 0) atomicMaxF(amaxOut, m);
}

__global__ __launch_bounds__(256) void final_add_kernel(
    const float* __restrict__ hraw, const float* __restrict__ t,
    const float* __restrict__ amaxT, float* __restrict__ u, u64 n,
    float* __restrict__ amaxOut)
{
  const float aT = *amaxT;
  u64 i = (u64)blockIdx.x * 256 + threadIdx.x;
  u64 stride = (u64)gridDim.x * 256;
  float m = 0.0f;
  for (; i < n; i += stride) {
    float v = hraw[i] + qdq_f(t[i], aT);
    u[i] = v;
    m = fmaxf(m, fabsf(v));
  }
  m = blockMax256(m);
  if (threadIdx.x == 0) atomicMaxF(amaxOut, m);
}

__global__ __launch_bounds__(256) void qdq_out_kernel(
    const float* __restrict__ u, const float* __restrict__ amaxU,
    float* __restrict__ o, u64 n)
{
  const float aU = *amaxU;
  u64 i = (u64)blockIdx.x * 256 + threadIdx.x;
  u64 stride = (u64)gridDim.x * 256;
  for (; i < n; i += stride) o[i] = qdq_f(u[i], aU);
}

// ---------------------------------------------------------------------------
// launch
// ---------------------------------------------------------------------------
extern "C" void kernel_launch(void* const* d_in, const int* in_sizes, int n_in,
                              void* d_out, int out_size, void* d_ws, size_t ws_size,
                              hipStream_t stream)
{
  const float* x   = (const float*)d_in[0];
  const float* g1  = (const float*)d_in[1];
  const float* bn1 = (const float*)d_in[2];
  const float* Wq  = (const float*)d_in[3];
  const float* bq  = (const float*)d_in[4];
  const float* Wk  = (const float*)d_in[5];
  const float* bk  = (const float*)d_in[6];
  const float* Wv  = (const float*)d_in[7];
  const float* bv  = (const float*)d_in[8];
  const float* Wo  = (const float*)d_in[9];
  const float* bo  = (const float*)d_in[10];
  const float* g2  = (const float*)d_in[11];
  const float* bn2 = (const float*)d_in[12];
  const float* W1  = (const float*)d_in[13];
  const float* bf1 = (const float*)d_in[14];
  const float* W2  = (const float*)d_in[15];
  const float* bf2 = (const float*)d_in[16];
  float* out = (float*)d_out;

  const u64 NBSD = (u64)Bdim * Sdim * Ddim;     // 8,388,608
  const u64 NB4  = NBSD * 4;
  const u64 DD   = (u64)Ddim * Ddim;

  char* Wb = (char*)d_ws;
  float*       Sc   = (float*)Wb;
  float*       U0   = (float*)(Wb + 1024);
  float*       U1   = (float*)(Wb + 1024 + NB4);
  float*       F    = (float*)(Wb + 1024 + 2 * NB4);
  signed char* A8   = (signed char*)(Wb + 1024 + 6 * NB4);
  signed char* Wq8  = A8 + NBSD;
  signed char* Wk8  = Wq8 + DD;
  signed char* Wv8  = Wk8 + DD;
  signed char* W18  = Wv8 + DD;
  signed char* W28  = W18 + 4 * DD;
  ushort_t*    WoBF = (ushort_t*)(W28 + 4 * DD);
  ushort_t*    OHI  = WoBF + DD;
  ushort_t*    OLO  = OHI + NBSD;
  signed char* G8   = (signed char*)U0;          // aliases U0 (dead by then)
  float* F0 = F;                                  // temp k (pre-attention)
  float* F1 = F + NBSD;                           // temp v (pre-attention)

  const u64 needBytes = (u64)((char*)(OLO + NBSD) - Wb);
  if (ws_size < needBytes) return;

  // scales: 0:h1 1:Wq 2:Wk 3:Wv 4:Wo 5:W1 6:W2 7:o_proj 8:t 9:h2 10:gelu 11:final
  init_scalars<<<1, 64, 0, stream>>>(Sc);

  ln_kernel<<<Bdim * Sdim, 256, 0, stream>>>(x, g1, bn1, nullptr, U0, Sc + 0);

  absmax_kernel<<<512, 256, 0, stream>>>(Wq, DD, Sc + 1);
  absmax_kernel<<<512, 256, 0, stream>>>(Wk, DD, Sc + 2);
  absmax_kernel<<<512, 256, 0, stream>>>(Wv, DD, Sc + 3);
  absmax_kernel<<<512, 256, 0, stream>>>(Wo, DD, Sc + 4);
  absmax_kernel<<<2048, 256, 0, stream>>>(W1, 4 * DD, Sc + 5);
  absmax_kernel<<<2048, 256, 0, stream>>>(W2, 4 * DD, Sc + 6);

  quant8_kernel<<<4096, 256, 0, stream>>>(U0, Sc + 0, A8, NBSD / 4);
  quant8_kernel<<<1024, 256, 0, stream>>>(Wq, Sc + 1, Wq8, DD / 4);
  quant8_kernel<<<1024, 256, 0, stream>>>(Wk, Sc + 2, Wk8, DD / 4);
  quant8_kernel<<<1024, 256, 0, stream>>>(Wv, Sc + 3, Wv8, DD / 4);
  quant8_kernel<<<4096, 256, 0, stream>>>(W1, Sc + 5, W18, DD);
  quant8_kernel<<<4096, 256, 0, stream>>>(W2, Sc + 6, W28, DD);
  quantbf_kernel<<<2048, 256, 0, stream>>>(Wo, Sc + 4, WoBF, DD);

  const int M = Bdim * Sdim;                     // 8192
  dim3 gP(Ddim / 128, M / 128);                  // (8, 64)
  gemm_i8<0><<<gP, 256, 0, stream>>>(A8, Wq8, bq, U1, M, Ddim, Ddim, Sc + 0, Sc + 1, nullptr);
  gemm_i8<0><<<gP, 256, 0, stream>>>(A8, Wk8, bk, F0, M, Ddim, Ddim, Sc + 0, Sc + 2, nullptr);
  gemm_i8<0><<<gP, 256, 0, stream>>>(A8, Wv8, bv, F1, M, Ddim, Ddim, Sc + 0, Sc + 3, nullptr);

  rope_kernel<<<(Bdim * Sdim * Hdim * 32) / 256, 256, 0, stream>>>(U1, F0);

  dim3 gAttn(Sdim / 64, Bdim * Hdim);            // (32, 64)
  attn_kernel<<<gAttn, 256, 0, stream>>>(U1, F0, F1, out);   // attn -> d_out

  split_bf16_kernel<<<4096, 256, 0, stream>>>(out, OHI, OLO, NBSD);
  gemm_bf16_wo<<<gP, 256, 0, stream>>>(OHI, OLO, WoBF, bo, U0, M, Ddim, Ddim, Sc + 4, Sc + 7);

  add_qdq_kernel<<<4096, 256, 0, stream>>>(U0, Sc + 7, x, U1, NBSD, Sc + 8);

  ln_kernel<<<Bdim * Sdim, 256, 0, stream>>>(U1, g2, bn2, Sc + 8, U0, Sc + 9);
  quant8_kernel<<<4096, 256, 0, stream>>>(U0, Sc + 9, A8, NBSD / 4);

  dim3 gF1(4 * Ddim / 128, M / 128);             // (32, 64)
  gemm_i8<1><<<gF1, 256, 0, stream>>>(A8, W18, bf1, F, M, 4 * Ddim, Ddim, Sc + 9, Sc + 5, Sc + 10);

  quant8_kernel<<<4096, 256, 0, stream>>>(F, Sc + 10, G8, NBSD);

  gemm_i8<0><<<gP, 256, 0, stream>>>(G8, W28, bf2, out, M, Ddim, 4 * Ddim, Sc + 10, Sc + 6, nullptr);

  final_add_kernel<<<4096, 256, 0, stream>>>(out, U1, Sc + 8, U0, NBSD, Sc + 11);
  qdq_out_kernel<<<4096, 256, 0, stream>>>(U0, Sc + 11, out, NBSD);
}

// Round 5
// 1351.157 us; speedup vs baseline: 6.6598x; 1.1958x over previous
//
#include <hip/hip_runtime.h>
#include <math.h>

#define Bdim 4
#define Sdim 2048
#define Ddim 1024
#define Hdim 16
#define HDdim 64

typedef unsigned long long u64;
typedef unsigned short ushort_t;
typedef int int4v __attribute__((ext_vector_type(4)));
typedef short short8v __attribute__((ext_vector_type(8)));
typedef float float4v __attribute__((ext_vector_type(4)));
typedef unsigned short us4v __attribute__((ext_vector_type(4)));

// ---------------------------------------------------------------------------
// helpers
// ---------------------------------------------------------------------------
__device__ __forceinline__ float qdq_f(float x, float amax) {
  float s = fmaxf(amax / 127.0f, 1e-8f);
  float r = rintf(x / s);
  r = fminf(fmaxf(r, -128.0f), 127.0f);
  return r * s;
}

__device__ __forceinline__ void atomicMaxF(float* a, float v) {
  atomicMax((int*)a, __float_as_int(v));   // valid: non-negative floats
}

__device__ __forceinline__ float blockMax256(float v) {
  __shared__ float sred[4];
  #pragma unroll
  for (int o = 32; o > 0; o >>= 1) v = fmaxf(v, __shfl_xor(v, o));
  if ((threadIdx.x & 63) == 0) sred[threadIdx.x >> 6] = v;
  __syncthreads();
  return fmaxf(fmaxf(sred[0], sred[1]), fmaxf(sred[2], sred[3]));
}

__device__ __forceinline__ ushort_t f2bf(float f) {  // RNE fp32->bf16
  unsigned u = __float_as_uint(f);
  return (ushort_t)((u + 0x7FFFu + ((u >> 16) & 1u)) >> 16);
}
__device__ __forceinline__ float bf2f(ushort_t h) {
  return __uint_as_float(((unsigned)h) << 16);
}

__global__ void init_scalars(float* s) { s[threadIdx.x] = 0.0f; }  // <<<1,64>>>

// ---------------------------------------------------------------------------
// absmax (grid-stride)
// ---------------------------------------------------------------------------
__global__ __launch_bounds__(256) void absmax_kernel(const float* __restrict__ x,
                                                     u64 n, float* __restrict__ amax) {
  u64 i = (u64)blockIdx.x * 256 + threadIdx.x;
  u64 stride = (u64)gridDim.x * 256;
  float m = 0.0f;
  for (; i < n; i += stride) m = fmaxf(m, fabsf(x[i]));
  m = blockMax256(m);
  if (threadIdx.x == 0) atomicMaxF(amax, m);
}

// ---------------------------------------------------------------------------
// quantize fp32 -> int8 (packed 4/thread)
// ---------------------------------------------------------------------------
__global__ __launch_bounds__(256) void quant8_kernel(
    const float* __restrict__ x, const float* __restrict__ amaxp,
    signed char* __restrict__ q, u64 n4)
{
  const float s = fmaxf(*amaxp / 127.0f, 1e-8f);
  u64 i = (u64)blockIdx.x * 256 + threadIdx.x;
  u64 stride = (u64)gridDim.x * 256;
  for (; i < n4; i += stride) {
    float4 v = ((const float4*)x)[i];
    int b0 = (int)fminf(fmaxf(rintf(v.x / s), -128.0f), 127.0f) & 255;
    int b1 = (int)fminf(fmaxf(rintf(v.y / s), -128.0f), 127.0f) & 255;
    int b2 = (int)fminf(fmaxf(rintf(v.z / s), -128.0f), 127.0f) & 255;
    int b3 = (int)fminf(fmaxf(rintf(v.w / s), -128.0f), 127.0f) & 255;
    ((unsigned*)q)[i] = (unsigned)(b0 | (b1 << 8) | (b2 << 16) | (b3 << 24));
  }
}

// quantize weight -> int stored as exact bf16 (|q|<=128 fits 8-bit mantissa)
__global__ __launch_bounds__(256) void quantbf_kernel(
    const float* __restrict__ w, const float* __restrict__ amaxp,
    ushort_t* __restrict__ o, u64 n)
{
  const float s = fmaxf(*amaxp / 127.0f, 1e-8f);
  u64 i = (u64)blockIdx.x * 256 + threadIdx.x;
  u64 stride = (u64)gridDim.x * 256;
  for (; i < n; i += stride) {
    float r = fminf(fmaxf(rintf(w[i] / s), -128.0f), 127.0f);
    o[i] = f2bf(r);
  }
}

// ---------------------------------------------------------------------------
// LayerNorm (one block per row of 1024), optional input qdq, output absmax
// ---------------------------------------------------------------------------
__global__ __launch_bounds__(256) void ln_kernel(
    const float* __restrict__ x, const float* __restrict__ g,
    const float* __restrict__ beta, const float* __restrict__ inAmax,
    float* __restrict__ y, float* __restrict__ amaxOut)
{
  __shared__ float sred[4];
  __shared__ float smv[2];
  const int tid = threadIdx.x;
  const u64 row = blockIdx.x;
  const float* xr = x + row * Ddim;
  float* yr = y + row * Ddim;
  float aIn = inAmax ? *inAmax : 0.0f;

  float vals[4];
  float sum = 0.0f;
  #pragma unroll
  for (int i = 0; i < 4; i++) {
    float v = xr[tid + (i << 8)];
    if (inAmax) v = qdq_f(v, aIn);
    vals[i] = v;
    sum += v;
  }
  #pragma unroll
  for (int o = 32; o > 0; o >>= 1) sum += __shfl_xor(sum, o);
  if ((tid & 63) == 0) sred[tid >> 6] = sum;
  __syncthreads();
  if (tid == 0) smv[0] = (sred[0] + sred[1] + sred[2] + sred[3]) * (1.0f / 1024.0f);
  __syncthreads();
  const float mean = smv[0];

  float dev = 0.0f;
  #pragma unroll
  for (int i = 0; i < 4; i++) { float d = vals[i] - mean; dev += d * d; }
  #pragma unroll
  for (int o = 32; o > 0; o >>= 1) dev += __shfl_xor(dev, o);
  if ((tid & 63) == 0) sred[tid >> 6] = dev;
  __syncthreads();
  if (tid == 0) {
    float var = (sred[0] + sred[1] + sred[2] + sred[3]) * (1.0f / 1024.0f);
    smv[1] = 1.0f / sqrtf(var + 1e-5f);
  }
  __syncthreads();
  const float inv = smv[1];

  float lmax = 0.0f;
  #pragma unroll
  for (int i = 0; i < 4; i++) {
    int c = tid + (i << 8);
    float ov = (vals[i] - mean) * inv * g[c] + beta[c];
    yr[c] = ov;
    lmax = fmaxf(lmax, fabsf(ov));
  }
  #pragma unroll
  for (int o = 32; o > 0; o >>= 1) lmax = fmaxf(lmax, __shfl_xor(lmax, o));
  __syncthreads();
  if ((tid & 63) == 0) sred[tid >> 6] = lmax;
  __syncthreads();
  if (tid == 0)
    atomicMaxF(amaxOut, fmaxf(fmaxf(sred[0], sred[1]), fmaxf(sred[2], sred[3])));
}

// ---------------------------------------------------------------------------
// i8 MFMA GEMM: C[M,N] = (A8[M,K] @ B8[N,K]^T)*sA*sB + bias[N]
// 128x128 tile, BK=64, 2x2 waves x 4x4 mfma_i32_16x16x64_i8 tiles.
// EPI: 0 none; 1 gelu+amax; 2 +qdq(T)+amax (fused residual add)
// ---------------------------------------------------------------------------
template <int EPI>
__global__ __launch_bounds__(256) void gemm_i8(
    const signed char* __restrict__ A8, const signed char* __restrict__ B8,
    const float* __restrict__ bias, float* __restrict__ C,
    int M, int N, int K,
    const float* __restrict__ sAp, const float* __restrict__ sBp,
    float* __restrict__ amaxOut,
    const float* __restrict__ Tm = nullptr,
    const float* __restrict__ amaxT = nullptr)
{
  __shared__ __align__(16) signed char As[128][80];
  __shared__ __align__(16) signed char Bs[128][80];
  const int tid = threadIdx.x;
  const int wave = tid >> 6, lane = tid & 63;
  const int quad = lane >> 4, l16 = lane & 15;
  const int wy = wave >> 1, wx = wave & 1;
  const int m0 = blockIdx.y << 7, n0 = blockIdx.x << 7;
  const float sA = fmaxf(*sAp / 127.0f, 1e-8f);
  const float sB = fmaxf(*sBp / 127.0f, 1e-8f);
  const float sAB = sA * sB;
  const float aT = (EPI == 2) ? *amaxT : 0.0f;

  const int sr = tid >> 2;            // staging row 0..63
  const int sc = (tid & 3) << 4;      // staging byte col 0/16/32/48

  int4v acc[4][4] = {};
  for (int k0 = 0; k0 < K; k0 += 64) {
    #pragma unroll
    for (int p = 0; p < 2; p++) {
      int r = sr + (p << 6);
      uint4 av = *(const uint4*)&A8[(u64)(m0 + r) * K + k0 + sc];
      uint4 bv = *(const uint4*)&B8[(u64)(n0 + r) * K + k0 + sc];
      *(uint4*)&As[r][sc] = av;
      *(uint4*)&Bs[r][sc] = bv;
    }
    __syncthreads();
    int4v af[4], bf[4];
    #pragma unroll
    for (int mt = 0; mt < 4; mt++)
      af[mt] = *(const int4v*)&As[(wy << 6) + (mt << 4) + l16][quad << 4];
    #pragma unroll
    for (int nt = 0; nt < 4; nt++)
      bf[nt] = *(const int4v*)&Bs[(wx << 6) + (nt << 4) + l16][quad << 4];
    #pragma unroll
    for (int mt = 0; mt < 4; mt++)
      #pragma unroll
      for (int nt = 0; nt < 4; nt++)
        acc[mt][nt] = __builtin_amdgcn_mfma_i32_16x16x64_i8(af[mt], bf[nt], acc[mt][nt], 0, 0, 0);
    __syncthreads();
  }

  float lmax = 0.0f;
  #pragma unroll
  for (int mt = 0; mt < 4; mt++) {
    #pragma unroll
    for (int reg = 0; reg < 4; reg++) {
      int row = m0 + (wy << 6) + (mt << 4) + (quad << 2) + reg;
      #pragma unroll
      for (int nt = 0; nt < 4; nt++) {
        int col = n0 + (wx << 6) + (nt << 4) + l16;
        float v = (float)acc[mt][nt][reg] * sAB + bias[col];
        if (EPI == 1) {
          v = 0.5f * v * (1.0f + erff(v * 0.70710678118654752440f));
          lmax = fmaxf(lmax, fabsf(v));
        }
        if (EPI == 2) {
          v += qdq_f(Tm[(u64)row * N + col], aT);
          lmax = fmaxf(lmax, fabsf(v));
        }
        C[(u64)row * N + col] = v;
      }
    }
  }
  if (EPI >= 1) {
    lmax = blockMax256(lmax);
    if (tid == 0) atomicMaxF(amaxOut, lmax);
  }
}

// ---------------------------------------------------------------------------
// bf16-split MFMA GEMM for Wo: C = ((Ahi+Alo)[M,K] @ Wq[N,K]^T)*sW + bias
// fused output absmax. mfma_f32_16x16x32_bf16, BK=32.
// ---------------------------------------------------------------------------
__global__ __launch_bounds__(256) void gemm_bf16_wo(
    const ushort_t* __restrict__ Ahi, const ushort_t* __restrict__ Alo,
    const ushort_t* __restrict__ Bw, const float* __restrict__ bias,
    float* __restrict__ C, int M, int N, int K,
    const float* __restrict__ sWp, float* __restrict__ amaxOut)
{
  __shared__ __align__(16) ushort_t Hs[128][40];
  __shared__ __align__(16) ushort_t Ls[128][40];
  __shared__ __align__(16) ushort_t Ws[128][40];
  const int tid = threadIdx.x;
  const int wave = tid >> 6, lane = tid & 63;
  const int quad = lane >> 4, l16 = lane & 15;
  const int wy = wave >> 1, wx = wave & 1;
  const int m0 = blockIdx.y << 7, n0 = blockIdx.x << 7;
  const float sW = fmaxf(*sWp / 127.0f, 1e-8f);

  const int sr = tid >> 2;
  const int sce = (tid & 3) << 3;

  float4v acc[4][4] = {};
  for (int k0 = 0; k0 < K; k0 += 32) {
    #pragma unroll
    for (int p = 0; p < 2; p++) {
      int r = sr + (p << 6);
      uint4 hv = *(const uint4*)&Ahi[(u64)(m0 + r) * K + k0 + sce];
      uint4 lv = *(const uint4*)&Alo[(u64)(m0 + r) * K + k0 + sce];
      uint4 wv = *(const uint4*)&Bw[(u64)(n0 + r) * K + k0 + sce];
      *(uint4*)&Hs[r][sce] = hv;
      *(uint4*)&Ls[r][sce] = lv;
      *(uint4*)&Ws[r][sce] = wv;
    }
    __syncthreads();
    short8v ah[4], al[4], bw[4];
    #pragma unroll
    for (int mt = 0; mt < 4; mt++) {
      ah[mt] = *(const short8v*)&Hs[(wy << 6) + (mt << 4) + l16][quad << 3];
      al[mt] = *(const short8v*)&Ls[(wy << 6) + (mt << 4) + l16][quad << 3];
    }
    #pragma unroll
    for (int nt = 0; nt < 4; nt++)
      bw[nt] = *(const short8v*)&Ws[(wx << 6) + (nt << 4) + l16][quad << 3];
    #pragma unroll
    for (int mt = 0; mt < 4; mt++)
      #pragma unroll
      for (int nt = 0; nt < 4; nt++) {
        acc[mt][nt] = __builtin_amdgcn_mfma_f32_16x16x32_bf16(ah[mt], bw[nt], acc[mt][nt], 0, 0, 0);
        acc[mt][nt] = __builtin_amdgcn_mfma_f32_16x16x32_bf16(al[mt], bw[nt], acc[mt][nt], 0, 0, 0);
      }
    __syncthreads();
  }

  float lmax = 0.0f;
  #pragma unroll
  for (int mt = 0; mt < 4; mt++) {
    #pragma unroll
    for (int reg = 0; reg < 4; reg++) {
      int row = m0 + (wy << 6) + (mt << 4) + (quad << 2) + reg;
      #pragma unroll
      for (int nt = 0; nt < 4; nt++) {
        int col = n0 + (wx << 6) + (nt << 4) + l16;
        float v = acc[mt][nt][reg] * sW + bias[col];
        lmax = fmaxf(lmax, fabsf(v));
        C[(u64)row * N + col] = v;
      }
    }
  }
  lmax = blockMax256(lmax);
  if (tid == 0) atomicMaxF(amaxOut, lmax);
}

// ---------------------------------------------------------------------------
// prep_attn: rope(q)*0.125, rope(k), hi/lo bf16 split, V transpose.
// In:  q,k,v fp32 [b][s][h][hd]
// Out: QH/QL/KH/KL ushort [bh][s][hd];  VTH/VTL ushort [bh][hd][s]
// grid (S/64, B*H), block 256.
// ---------------------------------------------------------------------------
__global__ __launch_bounds__(256) void prep_attn(
    const float* __restrict__ q, const float* __restrict__ k,
    const float* __restrict__ v,
    ushort_t* __restrict__ QH, ushort_t* __restrict__ QL,
    ushort_t* __restrict__ KH, ushort_t* __restrict__ KL,
    ushort_t* __restrict__ VTH, ushort_t* __restrict__ VTL)
{
  const int bh = blockIdx.y;
  const int b = bh >> 4, h = bh & 15;
  const int s0 = blockIdx.x << 6;
  const int tid = threadIdx.x;

  // --- q/k rope + scale + split (2048 pairs) ---
  #pragma unroll
  for (int i = 0; i < 8; i++) {
    int idx = tid + (i << 8);          // 0..2047
    int s = idx >> 5, hp = idx & 31;
    int sa = s0 + s;
    u64 gin = ((u64)(b * Sdim + sa) * Hdim + h) * HDdim + hp;
    float inv = powf(10000.0f, -(float)hp * (1.0f / 32.0f));
    float ang = (float)sa * inv;
    float cs = cosf(ang), sn = sinf(ang);
    float q1 = q[gin], q2 = q[gin + 32];
    float k1 = k[gin], k2 = k[gin + 32];
    float qo1 = (q1 * cs - q2 * sn) * 0.125f;
    float qo2 = (q1 * sn + q2 * cs) * 0.125f;
    float ko1 = k1 * cs - k2 * sn;
    float ko2 = k1 * sn + k2 * cs;
    u64 go = ((u64)bh * Sdim + sa) * HDdim + hp;
    ushort_t t;
    t = f2bf(qo1); QH[go]      = t; QL[go]      = f2bf(qo1 - bf2f(t));
    t = f2bf(qo2); QH[go + 32] = t; QL[go + 32] = f2bf(qo2 - bf2f(t));
    t = f2bf(ko1); KH[go]      = t; KL[go]      = f2bf(ko1 - bf2f(t));
    t = f2bf(ko2); KH[go + 32] = t; KL[go + 32] = f2bf(ko2 - bf2f(t));
  }

  // --- v: split + transpose via LDS ---
  __shared__ ushort_t VHs[64][66], VLs[64][66];
  #pragma unroll
  for (int i = 0; i < 4; i++) {
    int idx4 = tid + (i << 8);         // 0..1023
    int s = idx4 >> 4, c4 = (idx4 & 15) << 2;
    u64 gin = ((u64)(b * Sdim + s0 + s) * Hdim + h) * HDdim + c4;
    float4 vv = *(const float4*)&v[gin];
    float va[4] = {vv.x, vv.y, vv.z, vv.w};
    #pragma unroll
    for (int j = 0; j < 4; j++) {
      ushort_t vh = f2bf(va[j]);
      VHs[s][c4 + j] = vh;
      VLs[s][c4 + j] = f2bf(va[j] - bf2f(vh));
    }
  }
  __syncthreads();
  #pragma unroll
  for (int i = 0; i < 4; i++) {
    int idx4 = tid + (i << 8);
    int hd = idx4 >> 4, s4 = (idx4 & 15) << 2;
    us4v oh, ol;
    #pragma unroll
    for (int j = 0; j < 4; j++) { oh[j] = VHs[s4 + j][hd]; ol[j] = VLs[s4 + j][hd]; }
    u64 go = ((u64)bh * HDdim + hd) * Sdim + s0 + s4;
    *(us4v*)&VTH[go] = oh;
    *(us4v*)&VTL[go] = ol;
  }
}

// ---------------------------------------------------------------------------
// MFMA flash attention v2. Block = (b,h, 128 q-rows), 4 waves x 32 rows.
// Q frags in registers; K/V pre-split bf16 hi/lo staged row-major (no
// conflicts); P per-wave in LDS (no barrier). Output written as bf16 hi/lo
// (feeds gemm_bf16_wo directly). Score scale folded into Q by prep.
// LDS = (4*64 + 2*128) rows * 144B = 72 KB -> 2 blocks/CU.
// ---------------------------------------------------------------------------
__global__ __launch_bounds__(256) void attn_kernel(
    const ushort_t* __restrict__ QH, const ushort_t* __restrict__ QL,
    const ushort_t* __restrict__ KH, const ushort_t* __restrict__ KL,
    const ushort_t* __restrict__ VTH, const ushort_t* __restrict__ VTL,
    ushort_t* __restrict__ OHI, ushort_t* __restrict__ OLO)
{
  __shared__ __align__(16) ushort_t KHs[64][72], KLs[64][72];
  __shared__ __align__(16) ushort_t VHs[64][72], VLs[64][72];
  __shared__ __align__(16) ushort_t PHs[128][72], PLs[128][72];
  const int tid = threadIdx.x;
  const int wave = tid >> 6, lane = tid & 63;
  const int quad = lane >> 4, l16 = lane & 15;
  const int w32 = wave << 5;
  const int bh = blockIdx.y;
  const int b = bh >> 4, h = bh & 15;
  const int q0 = blockIdx.x << 7;
  const u64 bhS = (u64)bh * Sdim;

  // ---- Q fragments -> registers (A-layout: lane m=l16, k=quad*8+j) ----
  short8v qh[2][2], ql[2][2];
  #pragma unroll
  for (int mt = 0; mt < 2; mt++)
    #pragma unroll
    for (int kk = 0; kk < 2; kk++) {
      u64 g = (bhS + q0 + w32 + (mt << 4) + l16) * HDdim + (kk << 5) + (quad << 3);
      qh[mt][kk] = *(const short8v*)&QH[g];
      ql[mt][kk] = *(const short8v*)&QL[g];
    }

  float4v oacc[2][4] = {};
  float m_run[2][4], l_run[2][4];
  #pragma unroll
  for (int mt = 0; mt < 2; mt++)
    #pragma unroll
    for (int r = 0; r < 4; r++) { m_run[mt][r] = -INFINITY; l_run[mt][r] = 0.0f; }

  for (int j0 = 0; j0 < Sdim; j0 += 64) {
    __syncthreads();                   // prior iter's K/V reads complete
    #pragma unroll
    for (int i = 0; i < 2; i++) {
      int idx = tid + (i << 8);        // 0..511 = 64 rows x 8 chunks
      int r = idx >> 3, c8 = (idx & 7) << 3;
      u64 gk = (bhS + j0 + r) * HDdim + c8;
      *(uint4*)&KHs[r][c8] = *(const uint4*)&KH[gk];
      *(uint4*)&KLs[r][c8] = *(const uint4*)&KL[gk];
      u64 gv = ((u64)bh * HDdim + r) * Sdim + j0 + c8;
      *(uint4*)&VHs[r][c8] = *(const uint4*)&VTH[gv];
      *(uint4*)&VLs[r][c8] = *(const uint4*)&VTL[gv];
    }
    __syncthreads();

    // ---- scores (scale pre-folded into Q) ----
    float4v sc[2][4] = {};
    #pragma unroll
    for (int kk = 0; kk < 2; kk++)
      #pragma unroll
      for (int nt = 0; nt < 4; nt++) {
        short8v bh_ = *(const short8v*)&KHs[(nt << 4) + l16][(kk << 5) + (quad << 3)];
        short8v bl_ = *(const short8v*)&KLs[(nt << 4) + l16][(kk << 5) + (quad << 3)];
        #pragma unroll
        for (int mt = 0; mt < 2; mt++) {
          sc[mt][nt] = __builtin_amdgcn_mfma_f32_16x16x32_bf16(qh[mt][kk], bh_, sc[mt][nt], 0, 0, 0);
          sc[mt][nt] = __builtin_amdgcn_mfma_f32_16x16x32_bf16(qh[mt][kk], bl_, sc[mt][nt], 0, 0, 0);
          sc[mt][nt] = __builtin_amdgcn_mfma_f32_16x16x32_bf16(ql[mt][kk], bh_, sc[mt][nt], 0, 0, 0);
        }
      }

    // ---- online softmax; P -> per-wave LDS rows ----
    #pragma unroll
    for (int mt = 0; mt < 2; mt++)
      #pragma unroll
      for (int r = 0; r < 4; r++) {
        float s0 = sc[mt][0][r], s1 = sc[mt][1][r];
        float s2 = sc[mt][2][r], s3 = sc[mt][3][r];
        float mx = fmaxf(fmaxf(s0, s1), fmaxf(s2, s3));
        #pragma unroll
        for (int o = 8; o >= 1; o >>= 1) mx = fmaxf(mx, __shfl_xor(mx, o));
        float m_new = fmaxf(m_run[mt][r], mx);
        float alpha = expf(m_run[mt][r] - m_new);
        m_run[mt][r] = m_new;
        float p0 = expf(s0 - m_new), p1 = expf(s1 - m_new);
        float p2 = expf(s2 - m_new), p3 = expf(s3 - m_new);
        float rs = p0 + p1 + p2 + p3;
        #pragma unroll
        for (int o = 8; o >= 1; o >>= 1) rs += __shfl_xor(rs, o);
        l_run[mt][r] = l_run[mt][r] * alpha + rs;
        int prow = w32 + (mt << 4) + (quad << 2) + r;
        ushort_t t;
        t = f2bf(p0); PHs[prow][l16]      = t; PLs[prow][l16]      = f2bf(p0 - bf2f(t));
        t = f2bf(p1); PHs[prow][16 + l16] = t; PLs[prow][16 + l16] = f2bf(p1 - bf2f(t));
        t = f2bf(p2); PHs[prow][32 + l16] = t; PLs[prow][32 + l16] = f2bf(p2 - bf2f(t));
        t = f2bf(p3); PHs[prow][48 + l16] = t; PLs[prow][48 + l16] = f2bf(p3 - bf2f(t));
        #pragma unroll
        for (int nt = 0; nt < 4; nt++) oacc[mt][nt][r] *= alpha;
      }

    // ---- O += P V (per-wave P rows; compiler handles lgkmcnt RAW) ----
    #pragma unroll
    for (int kk = 0; kk < 2; kk++)
      #pragma unroll
      for (int mt = 0; mt < 2; mt++) {
        short8v ph = *(const short8v*)&PHs[w32 + (mt << 4) + l16][(kk << 5) + (quad << 3)];
        short8v pl = *(const short8v*)&PLs[w32 + (mt << 4) + l16][(kk << 5) + (quad << 3)];
        #pragma unroll
        for (int nt = 0; nt < 4; nt++) {
          short8v vh = *(const short8v*)&VHs[(nt << 4) + l16][(kk << 5) + (quad << 3)];
          short8v vl = *(const short8v*)&VLs[(nt << 4) + l16][(kk << 5) + (quad << 3)];
          oacc[mt][nt] = __builtin_amdgcn_mfma_f32_16x16x32_bf16(ph, vh, oacc[mt][nt], 0, 0, 0);
          oacc[mt][nt] = __builtin_amdgcn_mfma_f32_16x16x32_bf16(ph, vl, oacc[mt][nt], 0, 0, 0);
          oacc[mt][nt] = __builtin_amdgcn_mfma_f32_16x16x32_bf16(pl, vh, oacc[mt][nt], 0, 0, 0);
        }
      }
  }

  // ---- epilogue: o = O/l, split hi/lo, write [b][s][h][hd] ----
  #pragma unroll
  for (int mt = 0; mt < 2; mt++)
    #pragma unroll
    for (int r = 0; r < 4; r++) {
      float invl = 1.0f / l_run[mt][r];
      int srow = q0 + w32 + (mt << 4) + (quad << 2) + r;
      u64 gbase = ((u64)(b * Sdim + srow) * Hdim + h) * HDdim;
      #pragma unroll
      for (int nt = 0; nt < 4; nt++) {
        float o = oacc[mt][nt][r] * invl;
        ushort_t t = f2bf(o);
        OHI[gbase + (nt << 4) + l16] = t;
        OLO[gbase + (nt << 4) + l16] = f2bf(o - bf2f(t));
      }
    }
}

// ---------------------------------------------------------------------------
// elementwise stages
// ---------------------------------------------------------------------------
__global__ __launch_bounds__(256) void add_qdq_kernel(
    const float* __restrict__ a, const float* __restrict__ amaxA,
    const float* __restrict__ x, float* __restrict__ outp, u64 n,
    float* __restrict__ amaxOut)
{
  const float aA = *amaxA;
  u64 i = (u64)blockIdx.x * 256 + threadIdx.x;
  u64 stride = (u64)gridDim.x * 256;
  float m = 0.0f;
  for (; i < n; i += stride) {
    float t = qdq_f(a[i], aA) + x[i];
    outp[i] = t;
    m = fmaxf(m, fabsf(t));
  }
  m = blockMax256(m);
  if (threadIdx.x == 0) atomicMaxF(amaxOut, m);
}

__global__ __launch_bounds__(256) void qdq_out_kernel(
    const float* __restrict__ u, const float* __restrict__ amaxU,
    float* __restrict__ o, u64 n)
{
  const float aU = *amaxU;
  u64 i = (u64)blockIdx.x * 256 + threadIdx.x;
  u64 stride = (u64)gridDim.x * 256;
  for (; i < n; i += stride) o[i] = qdq_f(u[i], aU);
}

// ---------------------------------------------------------------------------
// launch
// ---------------------------------------------------------------------------
extern "C" void kernel_launch(void* const* d_in, const int* in_sizes, int n_in,
                              void* d_out, int out_size, void* d_ws, size_t ws_size,
                              hipStream_t stream)
{
  const float* x   = (const float*)d_in[0];
  const float* g1  = (const float*)d_in[1];
  const float* bn1 = (const float*)d_in[2];
  const float* Wq  = (const float*)d_in[3];
  const float* bq  = (const float*)d_in[4];
  const float* Wk  = (const float*)d_in[5];
  const float* bk  = (const float*)d_in[6];
  const float* Wv  = (const float*)d_in[7];
  const float* bv  = (const float*)d_in[8];
  const float* Wo  = (const float*)d_in[9];
  const float* bo  = (const float*)d_in[10];
  const float* g2  = (const float*)d_in[11];
  const float* bn2 = (const float*)d_in[12];
  const float* W1  = (const float*)d_in[13];
  const float* bf1 = (const float*)d_in[14];
  const float* W2  = (const float*)d_in[15];
  const float* bf2 = (const float*)d_in[16];
  float* out = (float*)d_out;

  const u64 NBSD = (u64)Bdim * Sdim * Ddim;     // 8,388,608
  const u64 NB4  = NBSD * 4;
  const u64 DD   = (u64)Ddim * Ddim;

  char* Wb = (char*)d_ws;
  float*       Sc   = (float*)Wb;
  float*       U0   = (float*)(Wb + 1024);
  float*       U1   = (float*)(Wb + 1024 + NB4);
  float*       F    = (float*)(Wb + 1024 + 2 * NB4);
  signed char* A8   = (signed char*)(Wb + 1024 + 6 * NB4);
  signed char* Wq8  = A8 + NBSD;
  signed char* Wk8  = Wq8 + DD;
  signed char* Wv8  = Wk8 + DD;
  signed char* W18  = Wv8 + DD;
  signed char* W28  = W18 + 4 * DD;
  ushort_t*    WoBF = (ushort_t*)(W28 + 4 * DD);

  // overlays (lifetime-checked):
  float* F0 = F;                                  // k fp32 (pre-attn), then o
  float* F1 = F + NBSD;                           // v fp32 (pre-attn)
  ushort_t* QHp = (ushort_t*)(F + 2 * NBSD);      // prep Q hi/lo in F2
  ushort_t* QLp = QHp + NBSD;
  ushort_t* KHp = (ushort_t*)(F + 3 * NBSD);      // prep K hi/lo in F3
  ushort_t* KLp = KHp + NBSD;
  ushort_t* VTH = (ushort_t*)U0;                  // prep V^T hi/lo in U0
  ushort_t* VTL = VTH + NBSD;
  ushort_t* OHI = (ushort_t*)U1;                  // attn out hi/lo in U1 (q dead)
  ushort_t* OLO = OHI + NBSD;
  signed char* G8 = (signed char*)U0;             // gelu int8 (h2 dead by then)

  const u64 needBytes = (u64)((char*)(WoBF + DD) - Wb);
  if (ws_size < needBytes) return;

  // scales: 0:h1 1:Wq 2:Wk 3:Wv 4:Wo 5:W1 6:W2 7:o_proj 8:t 9:h2 10:gelu 11:final
  init_scalars<<<1, 64, 0, stream>>>(Sc);

  ln_kernel<<<Bdim * Sdim, 256, 0, stream>>>(x, g1, bn1, nullptr, U0, Sc + 0);

  absmax_kernel<<<512, 256, 0, stream>>>(Wq, DD, Sc + 1);
  absmax_kernel<<<512, 256, 0, stream>>>(Wk, DD, Sc + 2);
  absmax_kernel<<<512, 256, 0, stream>>>(Wv, DD, Sc + 3);
  absmax_kernel<<<512, 256, 0, stream>>>(Wo, DD, Sc + 4);
  absmax_kernel<<<2048, 256, 0, stream>>>(W1, 4 * DD, Sc + 5);
  absmax_kernel<<<2048, 256, 0, stream>>>(W2, 4 * DD, Sc + 6);

  quant8_kernel<<<4096, 256, 0, stream>>>(U0, Sc + 0, A8, NBSD / 4);
  quant8_kernel<<<1024, 256, 0, stream>>>(Wq, Sc + 1, Wq8, DD / 4);
  quant8_kernel<<<1024, 256, 0, stream>>>(Wk, Sc + 2, Wk8, DD / 4);
  quant8_kernel<<<1024, 256, 0, stream>>>(Wv, Sc + 3, Wv8, DD / 4);
  quant8_kernel<<<4096, 256, 0, stream>>>(W1, Sc + 5, W18, DD);
  quant8_kernel<<<4096, 256, 0, stream>>>(W2, Sc + 6, W28, DD);
  quantbf_kernel<<<2048, 256, 0, stream>>>(Wo, Sc + 4, WoBF, DD);

  const int M = Bdim * Sdim;                     // 8192
  dim3 gP(Ddim / 128, M / 128);                  // (8, 64)
  gemm_i8<0><<<gP, 256, 0, stream>>>(A8, Wq8, bq, U1, M, Ddim, Ddim, Sc + 0, Sc + 1, nullptr);
  gemm_i8<0><<<gP, 256, 0, stream>>>(A8, Wk8, bk, F0, M, Ddim, Ddim, Sc + 0, Sc + 2, nullptr);
  gemm_i8<0><<<gP, 256, 0, stream>>>(A8, Wv8, bv, F1, M, Ddim, Ddim, Sc + 0, Sc + 3, nullptr);

  dim3 gPrep(Sdim / 64, Bdim * Hdim);            // (32, 64)
  prep_attn<<<gPrep, 256, 0, stream>>>(U1, F0, F1, QHp, QLp, KHp, KLp, VTH, VTL);

  dim3 gAttn(Sdim / 128, Bdim * Hdim);           // (16, 64)
  attn_kernel<<<gAttn, 256, 0, stream>>>(QHp, QLp, KHp, KLp, VTH, VTL, OHI, OLO);

  gemm_bf16_wo<<<gP, 256, 0, stream>>>(OHI, OLO, WoBF, bo, F0, M, Ddim, Ddim, Sc + 4, Sc + 7);

  // t = fq(o) + x -> U1 (OHI/OLO dead)
  add_qdq_kernel<<<4096, 256, 0, stream>>>(F0, Sc + 7, x, U1, NBSD, Sc + 8);

  ln_kernel<<<Bdim * Sdim, 256, 0, stream>>>(U1, g2, bn2, Sc + 8, U0, Sc + 9);
  quant8_kernel<<<4096, 256, 0, stream>>>(U0, Sc + 9, A8, NBSD / 4);

  dim3 gF1(4 * Ddim / 128, M / 128);             // (32, 64)
  gemm_i8<1><<<gF1, 256, 0, stream>>>(A8, W18, bf1, F, M, 4 * Ddim, Ddim, Sc + 9, Sc + 5, Sc + 10);

  quant8_kernel<<<4096, 256, 0, stream>>>(F, Sc + 10, G8, NBSD);

  // FFN2 with fused residual: u = acc*s + bias + qdq(t) -> d_out, amax Sc11
  gemm_i8<2><<<gP, 256, 0, stream>>>(G8, W28, bf2, out, M, Ddim, 4 * Ddim,
                                     Sc + 10, Sc + 6, Sc + 11, U1, Sc + 8);

  qdq_out_kernel<<<4096, 256, 0, stream>>>(out, Sc + 11, out, NBSD);
}

// Round 6
// 1184.162 us; speedup vs baseline: 7.5990x; 1.1410x over previous
//
#include <hip/hip_runtime.h>
#include <math.h>

#define Bdim 4
#define Sdim 2048
#define Ddim 1024
#define Hdim 16
#define HDdim 64

typedef unsigned long long u64;
typedef unsigned short ushort_t;
typedef int int4v __attribute__((ext_vector_type(4)));
typedef short short8v __attribute__((ext_vector_type(8)));
typedef float float4v __attribute__((ext_vector_type(4)));
typedef unsigned short us4v __attribute__((ext_vector_type(4)));

// ---------------------------------------------------------------------------
// helpers
// ---------------------------------------------------------------------------
__device__ __forceinline__ float qdq_f(float x, float amax) {
  float s = fmaxf(amax / 127.0f, 1e-8f);
  float r = rintf(x / s);
  r = fminf(fmaxf(r, -128.0f), 127.0f);
  return r * s;
}

__device__ __forceinline__ void atomicMaxF(float* a, float v) {
  atomicMax((int*)a, __float_as_int(v));   // valid: non-negative floats
}

__device__ __forceinline__ float blockMax256(float v) {
  __shared__ float sred[4];
  #pragma unroll
  for (int o = 32; o > 0; o >>= 1) v = fmaxf(v, __shfl_xor(v, o));
  if ((threadIdx.x & 63) == 0) sred[threadIdx.x >> 6] = v;
  __syncthreads();
  return fmaxf(fmaxf(sred[0], sred[1]), fmaxf(sred[2], sred[3]));
}

__device__ __forceinline__ ushort_t f2bf(float f) {  // RNE fp32->bf16
  unsigned u = __float_as_uint(f);
  return (ushort_t)((u + 0x7FFFu + ((u >> 16) & 1u)) >> 16);
}
__device__ __forceinline__ float bf2f(ushort_t h) {
  return __uint_as_float(((unsigned)h) << 16);
}

__global__ void init_scalars(float* s) { s[threadIdx.x] = 0.0f; }  // <<<1,256>>>

// ---------------------------------------------------------------------------
// merged absmax of 6 weights (segmented grid-stride)
// ---------------------------------------------------------------------------
__global__ __launch_bounds__(256) void absmax6_kernel(
    const float* __restrict__ Wq, const float* __restrict__ Wk,
    const float* __restrict__ Wv, const float* __restrict__ Wo,
    const float* __restrict__ W1, const float* __restrict__ W2,
    float* __restrict__ Sc)
{
  const u64 DD = (u64)Ddim * Ddim;
  int blk = blockIdx.x;
  const float* src; float* dst; u64 lb, nb, n;
  if (blk < 256)       { src = Wq; dst = Sc + 1; lb = blk;        nb = 256;  n = DD; }
  else if (blk < 512)  { src = Wk; dst = Sc + 2; lb = blk - 256;  nb = 256;  n = DD; }
  else if (blk < 768)  { src = Wv; dst = Sc + 3; lb = blk - 512;  nb = 256;  n = DD; }
  else if (blk < 1024) { src = Wo; dst = Sc + 4; lb = blk - 768;  nb = 256;  n = DD; }
  else if (blk < 2048) { src = W1; dst = Sc + 5; lb = blk - 1024; nb = 1024; n = 4 * DD; }
  else                 { src = W2; dst = Sc + 6; lb = blk - 2048; nb = 1024; n = 4 * DD; }
  u64 i = lb * 256 + threadIdx.x;
  u64 stride = nb * 256;
  float m = 0.0f;
  for (; i < n; i += stride) m = fmaxf(m, fabsf(src[i]));
  m = blockMax256(m);
  if (threadIdx.x == 0) atomicMaxF(dst, m);
}

// ---------------------------------------------------------------------------
// merged weight quantization: Wq/Wk/Wv/W1/W2 -> int8, Wo -> int-in-bf16
// ---------------------------------------------------------------------------
__global__ __launch_bounds__(256) void quantw_kernel(
    const float* __restrict__ Wq, const float* __restrict__ Wk,
    const float* __restrict__ Wv, const float* __restrict__ Wo,
    const float* __restrict__ W1, const float* __restrict__ W2,
    signed char* __restrict__ Wq8, signed char* __restrict__ Wk8,
    signed char* __restrict__ Wv8, ushort_t* __restrict__ WoBF,
    signed char* __restrict__ W18, signed char* __restrict__ W28,
    const float* __restrict__ Sc)
{
  const u64 DD = (u64)Ddim * Ddim;
  int blk = blockIdx.x;
  if (blk < 2816) {   // int8 path (float4 units)
    const float* src; signed char* dst; float sa; u64 lb, nb, n4;
    if (blk < 256)       { src = Wq; dst = Wq8; sa = Sc[1]; lb = blk;        nb = 256;  n4 = DD / 4; }
    else if (blk < 512)  { src = Wk; dst = Wk8; sa = Sc[2]; lb = blk - 256;  nb = 256;  n4 = DD / 4; }
    else if (blk < 768)  { src = Wv; dst = Wv8; sa = Sc[3]; lb = blk - 512;  nb = 256;  n4 = DD / 4; }
    else if (blk < 1792) { src = W1; dst = W18; sa = Sc[5]; lb = blk - 768;  nb = 1024; n4 = DD; }
    else                 { src = W2; dst = W28; sa = Sc[6]; lb = blk - 1792; nb = 1024; n4 = DD; }
    const float s = fmaxf(sa / 127.0f, 1e-8f);
    u64 i = lb * 256 + threadIdx.x;
    u64 stride = nb * 256;
    for (; i < n4; i += stride) {
      float4 v = ((const float4*)src)[i];
      int b0 = (int)fminf(fmaxf(rintf(v.x / s), -128.0f), 127.0f) & 255;
      int b1 = (int)fminf(fmaxf(rintf(v.y / s), -128.0f), 127.0f) & 255;
      int b2 = (int)fminf(fmaxf(rintf(v.z / s), -128.0f), 127.0f) & 255;
      int b3 = (int)fminf(fmaxf(rintf(v.w / s), -128.0f), 127.0f) & 255;
      ((unsigned*)dst)[i] = (unsigned)(b0 | (b1 << 8) | (b2 << 16) | (b3 << 24));
    }
  } else {            // Wo -> exact int in bf16
    const float s = fmaxf(Sc[4] / 127.0f, 1e-8f);
    u64 i = (u64)(blk - 2816) * 256 + threadIdx.x;
    u64 stride = 1024ull * 256;
    for (; i < DD; i += stride) {
      float r = fminf(fmaxf(rintf(Wo[i] / s), -128.0f), 127.0f);
      WoBF[i] = f2bf(r);
    }
  }
}

// ---------------------------------------------------------------------------
// quantize fp32 -> int8 (packed 4/thread) — activations
// ---------------------------------------------------------------------------
__global__ __launch_bounds__(256) void quant8_kernel(
    const float* __restrict__ x, const float* __restrict__ amaxp,
    signed char* __restrict__ q, u64 n4)
{
  const float s = fmaxf(*amaxp / 127.0f, 1e-8f);
  u64 i = (u64)blockIdx.x * 256 + threadIdx.x;
  u64 stride = (u64)gridDim.x * 256;
  for (; i < n4; i += stride) {
    float4 v = ((const float4*)x)[i];
    int b0 = (int)fminf(fmaxf(rintf(v.x / s), -128.0f), 127.0f) & 255;
    int b1 = (int)fminf(fmaxf(rintf(v.y / s), -128.0f), 127.0f) & 255;
    int b2 = (int)fminf(fmaxf(rintf(v.z / s), -128.0f), 127.0f) & 255;
    int b3 = (int)fminf(fmaxf(rintf(v.w / s), -128.0f), 127.0f) & 255;
    ((unsigned*)q)[i] = (unsigned)(b0 | (b1 << 8) | (b2 << 16) | (b3 << 24));
  }
}

// ---------------------------------------------------------------------------
// LayerNorm (one block per row of 1024), optional input qdq, output absmax
// ---------------------------------------------------------------------------
__global__ __launch_bounds__(256) void ln_kernel(
    const float* __restrict__ x, const float* __restrict__ g,
    const float* __restrict__ beta, const float* __restrict__ inAmax,
    float* __restrict__ y, float* __restrict__ amaxOut)
{
  __shared__ float sred[4];
  __shared__ float smv[2];
  const int tid = threadIdx.x;
  const u64 row = blockIdx.x;
  const float* xr = x + row * Ddim;
  float* yr = y + row * Ddim;
  float aIn = inAmax ? *inAmax : 0.0f;

  float vals[4];
  float sum = 0.0f;
  #pragma unroll
  for (int i = 0; i < 4; i++) {
    float v = xr[tid + (i << 8)];
    if (inAmax) v = qdq_f(v, aIn);
    vals[i] = v;
    sum += v;
  }
  #pragma unroll
  for (int o = 32; o > 0; o >>= 1) sum += __shfl_xor(sum, o);
  if ((tid & 63) == 0) sred[tid >> 6] = sum;
  __syncthreads();
  if (tid == 0) smv[0] = (sred[0] + sred[1] + sred[2] + sred[3]) * (1.0f / 1024.0f);
  __syncthreads();
  const float mean = smv[0];

  float dev = 0.0f;
  #pragma unroll
  for (int i = 0; i < 4; i++) { float d = vals[i] - mean; dev += d * d; }
  #pragma unroll
  for (int o = 32; o > 0; o >>= 1) dev += __shfl_xor(dev, o);
  if ((tid & 63) == 0) sred[tid >> 6] = dev;
  __syncthreads();
  if (tid == 0) {
    float var = (sred[0] + sred[1] + sred[2] + sred[3]) * (1.0f / 1024.0f);
    smv[1] = 1.0f / sqrtf(var + 1e-5f);
  }
  __syncthreads();
  const float inv = smv[1];

  float lmax = 0.0f;
  #pragma unroll
  for (int i = 0; i < 4; i++) {
    int c = tid + (i << 8);
    float ov = (vals[i] - mean) * inv * g[c] + beta[c];
    yr[c] = ov;
    lmax = fmaxf(lmax, fabsf(ov));
  }
  #pragma unroll
  for (int o = 32; o > 0; o >>= 1) lmax = fmaxf(lmax, __shfl_xor(lmax, o));
  __syncthreads();
  if ((tid & 63) == 0) sred[tid >> 6] = lmax;
  __syncthreads();
  if (tid == 0)
    atomicMaxF(amaxOut, fmaxf(fmaxf(sred[0], sred[1]), fmaxf(sred[2], sred[3])));
}

// ---------------------------------------------------------------------------
// i8 MFMA GEMM: C[M,N] = (A8[M,K] @ B8[N,K]^T)*sA*sB + bias[N]
// 128x128 tile, BK=64, 2x2 waves x 4x4 mfma_i32_16x16x64_i8 tiles.
// EPI: 0 none; 1 gelu+amax; 2 +qdq(T)+amax (fused residual add)
// ---------------------------------------------------------------------------
template <int EPI>
__global__ __launch_bounds__(256) void gemm_i8(
    const signed char* __restrict__ A8, const signed char* __restrict__ B8,
    const float* __restrict__ bias, float* __restrict__ C,
    int M, int N, int K,
    const float* __restrict__ sAp, const float* __restrict__ sBp,
    float* __restrict__ amaxOut,
    const float* __restrict__ Tm = nullptr,
    const float* __restrict__ amaxT = nullptr)
{
  __shared__ __align__(16) signed char As[128][80];
  __shared__ __align__(16) signed char Bs[128][80];
  const int tid = threadIdx.x;
  const int wave = tid >> 6, lane = tid & 63;
  const int quad = lane >> 4, l16 = lane & 15;
  const int wy = wave >> 1, wx = wave & 1;
  const int m0 = blockIdx.y << 7, n0 = blockIdx.x << 7;
  const float sA = fmaxf(*sAp / 127.0f, 1e-8f);
  const float sB = fmaxf(*sBp / 127.0f, 1e-8f);
  const float sAB = sA * sB;
  const float aT = (EPI == 2) ? *amaxT : 0.0f;

  const int sr = tid >> 2;            // staging row 0..63
  const int sc = (tid & 3) << 4;      // staging byte col 0/16/32/48

  int4v acc[4][4] = {};
  for (int k0 = 0; k0 < K; k0 += 64) {
    #pragma unroll
    for (int p = 0; p < 2; p++) {
      int r = sr + (p << 6);
      uint4 av = *(const uint4*)&A8[(u64)(m0 + r) * K + k0 + sc];
      uint4 bv = *(const uint4*)&B8[(u64)(n0 + r) * K + k0 + sc];
      *(uint4*)&As[r][sc] = av;
      *(uint4*)&Bs[r][sc] = bv;
    }
    __syncthreads();
    int4v af[4], bf[4];
    #pragma unroll
    for (int mt = 0; mt < 4; mt++)
      af[mt] = *(const int4v*)&As[(wy << 6) + (mt << 4) + l16][quad << 4];
    #pragma unroll
    for (int nt = 0; nt < 4; nt++)
      bf[nt] = *(const int4v*)&Bs[(wx << 6) + (nt << 4) + l16][quad << 4];
    #pragma unroll
    for (int mt = 0; mt < 4; mt++)
      #pragma unroll
      for (int nt = 0; nt < 4; nt++)
        acc[mt][nt] = __builtin_amdgcn_mfma_i32_16x16x64_i8(af[mt], bf[nt], acc[mt][nt], 0, 0, 0);
    __syncthreads();
  }

  float lmax = 0.0f;
  #pragma unroll
  for (int mt = 0; mt < 4; mt++) {
    #pragma unroll
    for (int reg = 0; reg < 4; reg++) {
      int row = m0 + (wy << 6) + (mt << 4) + (quad << 2) + reg;
      #pragma unroll
      for (int nt = 0; nt < 4; nt++) {
        int col = n0 + (wx << 6) + (nt << 4) + l16;
        float v = (float)acc[mt][nt][reg] * sAB + bias[col];
        if (EPI == 1) {
          v = 0.5f * v * (1.0f + erff(v * 0.70710678118654752440f));
          lmax = fmaxf(lmax, fabsf(v));
        }
        if (EPI == 2) {
          v += qdq_f(Tm[(u64)row * N + col], aT);
          lmax = fmaxf(lmax, fabsf(v));
        }
        C[(u64)row * N + col] = v;
      }
    }
  }
  if (EPI >= 1) {
    lmax = blockMax256(lmax);
    if (tid == 0) atomicMaxF(amaxOut, lmax);
  }
}

// ---------------------------------------------------------------------------
// bf16-split MFMA GEMM for Wo: C = ((Ahi+Alo)[M,K] @ Wq[N,K]^T)*sW + bias
// ---------------------------------------------------------------------------
__global__ __launch_bounds__(256) void gemm_bf16_wo(
    const ushort_t* __restrict__ Ahi, const ushort_t* __restrict__ Alo,
    const ushort_t* __restrict__ Bw, const float* __restrict__ bias,
    float* __restrict__ C, int M, int N, int K,
    const float* __restrict__ sWp, float* __restrict__ amaxOut)
{
  __shared__ __align__(16) ushort_t Hs[128][40];
  __shared__ __align__(16) ushort_t Ls[128][40];
  __shared__ __align__(16) ushort_t Ws[128][40];
  const int tid = threadIdx.x;
  const int wave = tid >> 6, lane = tid & 63;
  const int quad = lane >> 4, l16 = lane & 15;
  const int wy = wave >> 1, wx = wave & 1;
  const int m0 = blockIdx.y << 7, n0 = blockIdx.x << 7;
  const float sW = fmaxf(*sWp / 127.0f, 1e-8f);

  const int sr = tid >> 2;
  const int sce = (tid & 3) << 3;

  float4v acc[4][4] = {};
  for (int k0 = 0; k0 < K; k0 += 32) {
    #pragma unroll
    for (int p = 0; p < 2; p++) {
      int r = sr + (p << 6);
      uint4 hv = *(const uint4*)&Ahi[(u64)(m0 + r) * K + k0 + sce];
      uint4 lv = *(const uint4*)&Alo[(u64)(m0 + r) * K + k0 + sce];
      uint4 wv = *(const uint4*)&Bw[(u64)(n0 + r) * K + k0 + sce];
      *(uint4*)&Hs[r][sce] = hv;
      *(uint4*)&Ls[r][sce] = lv;
      *(uint4*)&Ws[r][sce] = wv;
    }
    __syncthreads();
    short8v ah[4], al[4], bw[4];
    #pragma unroll
    for (int mt = 0; mt < 4; mt++) {
      ah[mt] = *(const short8v*)&Hs[(wy << 6) + (mt << 4) + l16][quad << 3];
      al[mt] = *(const short8v*)&Ls[(wy << 6) + (mt << 4) + l16][quad << 3];
    }
    #pragma unroll
    for (int nt = 0; nt < 4; nt++)
      bw[nt] = *(const short8v*)&Ws[(wx << 6) + (nt << 4) + l16][quad << 3];
    #pragma unroll
    for (int mt = 0; mt < 4; mt++)
      #pragma unroll
      for (int nt = 0; nt < 4; nt++) {
        acc[mt][nt] = __builtin_amdgcn_mfma_f32_16x16x32_bf16(ah[mt], bw[nt], acc[mt][nt], 0, 0, 0);
        acc[mt][nt] = __builtin_amdgcn_mfma_f32_16x16x32_bf16(al[mt], bw[nt], acc[mt][nt], 0, 0, 0);
      }
    __syncthreads();
  }

  float lmax = 0.0f;
  #pragma unroll
  for (int mt = 0; mt < 4; mt++) {
    #pragma unroll
    for (int reg = 0; reg < 4; reg++) {
      int row = m0 + (wy << 6) + (mt << 4) + (quad << 2) + reg;
      #pragma unroll
      for (int nt = 0; nt < 4; nt++) {
        int col = n0 + (wx << 6) + (nt << 4) + l16;
        float v = acc[mt][nt][reg] * sW + bias[col];
        lmax = fmaxf(lmax, fabsf(v));
        C[(u64)row * N + col] = v;
      }
    }
  }
  lmax = blockMax256(lmax);
  if (tid == 0) atomicMaxF(amaxOut, lmax);
}

// ---------------------------------------------------------------------------
// prep_attn: rope(q)*0.125, rope(k), hi/lo bf16 split, V transpose,
// per-row ||q||2 -> NQ, per-bh max ||k||2 -> KMX (for static-max softmax).
// ---------------------------------------------------------------------------
__global__ __launch_bounds__(256) void prep_attn(
    const float* __restrict__ q, const float* __restrict__ k,
    const float* __restrict__ v,
    ushort_t* __restrict__ QH, ushort_t* __restrict__ QL,
    ushort_t* __restrict__ KH, ushort_t* __restrict__ KL,
    ushort_t* __restrict__ VTH, ushort_t* __restrict__ VTL,
    float* __restrict__ NQ, float* __restrict__ KMX)
{
  const int bh = blockIdx.y;
  const int b = bh >> 4, h = bh & 15;
  const int s0 = blockIdx.x << 6;
  const int tid = threadIdx.x;
  float kml = 0.0f;

  // --- q/k rope + scale + split + norms (2048 pairs) ---
  #pragma unroll
  for (int i = 0; i < 8; i++) {
    int idx = tid + (i << 8);          // 0..2047
    int s = idx >> 5, hp = idx & 31;
    int sa = s0 + s;
    u64 gin = ((u64)(b * Sdim + sa) * Hdim + h) * HDdim + hp;
    float inv = powf(10000.0f, -(float)hp * (1.0f / 32.0f));
    float ang = (float)sa * inv;
    float cs = cosf(ang), sn = sinf(ang);
    float q1 = q[gin], q2 = q[gin + 32];
    float k1 = k[gin], k2 = k[gin + 32];
    float qo1 = (q1 * cs - q2 * sn) * 0.125f;
    float qo2 = (q1 * sn + q2 * cs) * 0.125f;
    float ko1 = k1 * cs - k2 * sn;
    float ko2 = k1 * sn + k2 * cs;
    u64 go = ((u64)bh * Sdim + sa) * HDdim + hp;
    ushort_t t;
    t = f2bf(qo1); QH[go]      = t; QL[go]      = f2bf(qo1 - bf2f(t));
    t = f2bf(qo2); QH[go + 32] = t; QL[go + 32] = f2bf(qo2 - bf2f(t));
    t = f2bf(ko1); KH[go]      = t; KL[go]      = f2bf(ko1 - bf2f(t));
    t = f2bf(ko2); KH[go + 32] = t; KL[go + 32] = f2bf(ko2 - bf2f(t));
    // row norms (reduce over hp = low 5 lane bits)
    float nq2 = qo1 * qo1 + qo2 * qo2;
    float nk2 = ko1 * ko1 + ko2 * ko2;
    #pragma unroll
    for (int o = 16; o >= 1; o >>= 1) {
      nq2 += __shfl_xor(nq2, o);
      nk2 += __shfl_xor(nk2, o);
    }
    if (hp == 0) {
      NQ[(u64)bh * Sdim + sa] = sqrtf(nq2);
      kml = fmaxf(kml, sqrtf(nk2));
    }
  }
  kml = blockMax256(kml);
  if (tid == 0) atomicMaxF(&KMX[bh], kml);

  // --- v: split + transpose via LDS ---
  __shared__ ushort_t VHs[64][66], VLs[64][66];
  #pragma unroll
  for (int i = 0; i < 4; i++) {
    int idx4 = tid + (i << 8);         // 0..1023
    int s = idx4 >> 4, c4 = (idx4 & 15) << 2;
    u64 gin = ((u64)(b * Sdim + s0 + s) * Hdim + h) * HDdim + c4;
    float4 vv = *(const float4*)&v[gin];
    float va[4] = {vv.x, vv.y, vv.z, vv.w};
    #pragma unroll
    for (int j = 0; j < 4; j++) {
      ushort_t vh = f2bf(va[j]);
      VHs[s][c4 + j] = vh;
      VLs[s][c4 + j] = f2bf(va[j] - bf2f(vh));
    }
  }
  __syncthreads();
  #pragma unroll
  for (int i = 0; i < 4; i++) {
    int idx4 = tid + (i << 8);
    int hd = idx4 >> 4, s4 = (idx4 & 15) << 2;
    us4v oh, ol;
    #pragma unroll
    for (int j = 0; j < 4; j++) { oh[j] = VHs[s4 + j][hd]; ol[j] = VLs[s4 + j][hd]; }
    u64 go = ((u64)bh * HDdim + hd) * Sdim + s0 + s4;
    *(us4v*)&VTH[go] = oh;
    *(us4v*)&VTL[go] = ol;
  }
}

// ---------------------------------------------------------------------------
// MFMA flash attention v3: static-max softmax (M_r = ||q_r||*Kmax bound),
// P stored fp32 (split to bf16 hi/lo at frag read), V-frags hoisted,
// l-reduction hoisted out of the loop. Block = 128 q-rows, 4 waves x 32.
// LDS = 4*9216 (K/V) + 34816 (P fp32) = 71680 -> 2 blocks/CU.
// ---------------------------------------------------------------------------
__global__ __launch_bounds__(256) void attn_kernel(
    const ushort_t* __restrict__ QH, const ushort_t* __restrict__ QL,
    const ushort_t* __restrict__ KH, const ushort_t* __restrict__ KL,
    const ushort_t* __restrict__ VTH, const ushort_t* __restrict__ VTL,
    const float* __restrict__ NQ, const float* __restrict__ KMX,
    ushort_t* __restrict__ OHI, ushort_t* __restrict__ OLO)
{
  __shared__ __align__(16) ushort_t KHs[64][72], KLs[64][72];
  __shared__ __align__(16) ushort_t VHs[64][72], VLs[64][72];
  __shared__ __align__(16) float PF[128][68];
  const int tid = threadIdx.x;
  const int wave = tid >> 6, lane = tid & 63;
  const int quad = lane >> 4, l16 = lane & 15;
  const int w32 = wave << 5;
  const int bh = blockIdx.y;
  const int b = bh >> 4, h = bh & 15;
  const int q0 = blockIdx.x << 7;
  const u64 bhS = (u64)bh * Sdim;

  // ---- Q fragments -> registers ----
  short8v qh[2][2], ql[2][2];
  #pragma unroll
  for (int mt = 0; mt < 2; mt++)
    #pragma unroll
    for (int kk = 0; kk < 2; kk++) {
      u64 g = (bhS + q0 + w32 + (mt << 4) + l16) * HDdim + (kk << 5) + (quad << 3);
      qh[mt][kk] = *(const short8v*)&QH[g];
      ql[mt][kk] = *(const short8v*)&QL[g];
    }

  // ---- static-max bounds per owned row ----
  const float kmax = KMX[bh] * 1.0009765625f;    // tiny slack; exp(+eps) harmless
  float Mb[2][4], lsum[2][4];
  #pragma unroll
  for (int mt = 0; mt < 2; mt++)
    #pragma unroll
    for (int r = 0; r < 4; r++) {
      Mb[mt][r] = NQ[bhS + q0 + w32 + (mt << 4) + (quad << 2) + r] * kmax;
      lsum[mt][r] = 0.0f;
    }

  float4v oacc[2][4] = {};

  for (int j0 = 0; j0 < Sdim; j0 += 64) {
    __syncthreads();
    #pragma unroll
    for (int i = 0; i < 2; i++) {
      int idx = tid + (i << 8);        // 0..511 = 64 rows x 8 chunks
      int r = idx >> 3, c8 = (idx & 7) << 3;
      u64 gk = (bhS + j0 + r) * HDdim + c8;
      *(uint4*)&KHs[r][c8] = *(const uint4*)&KH[gk];
      *(uint4*)&KLs[r][c8] = *(const uint4*)&KL[gk];
      u64 gv = ((u64)bh * HDdim + r) * Sdim + j0 + c8;
      *(uint4*)&VHs[r][c8] = *(const uint4*)&VTH[gv];
      *(uint4*)&VLs[r][c8] = *(const uint4*)&VTL[gv];
    }
    __syncthreads();

    // ---- scores (scale pre-folded into Q) ----
    float4v sc[2][4] = {};
    #pragma unroll
    for (int kk = 0; kk < 2; kk++)
      #pragma unroll
      for (int nt = 0; nt < 4; nt++) {
        short8v bh_ = *(const short8v*)&KHs[(nt << 4) + l16][(kk << 5) + (quad << 3)];
        short8v bl_ = *(const short8v*)&KLs[(nt << 4) + l16][(kk << 5) + (quad << 3)];
        #pragma unroll
        for (int mt = 0; mt < 2; mt++) {
          sc[mt][nt] = __builtin_amdgcn_mfma_f32_16x16x32_bf16(qh[mt][kk], bh_, sc[mt][nt], 0, 0, 0);
          sc[mt][nt] = __builtin_amdgcn_mfma_f32_16x16x32_bf16(qh[mt][kk], bl_, sc[mt][nt], 0, 0, 0);
          sc[mt][nt] = __builtin_amdgcn_mfma_f32_16x16x32_bf16(ql[mt][kk], bh_, sc[mt][nt], 0, 0, 0);
        }
      }

    // ---- static-max softmax: p = exp(s - M), accumulate partial l ----
    #pragma unroll
    for (int mt = 0; mt < 2; mt++)
      #pragma unroll
      for (int r = 0; r < 4; r++) {
        int prow = w32 + (mt << 4) + (quad << 2) + r;
        float lacc = 0.0f;
        #pragma unroll
        for (int nt = 0; nt < 4; nt++) {
          float p = __expf(sc[mt][nt][r] - Mb[mt][r]);
          lacc += p;
          PF[prow][(nt << 4) + l16] = p;
        }
        lsum[mt][r] += lacc;
      }
    // no barrier: each wave reads only its own P rows (RAW handled by lgkmcnt)

    // ---- O += P V (V-frags hoisted over mt) ----
    #pragma unroll
    for (int kk = 0; kk < 2; kk++) {
      short8v vh[4], vl[4];
      #pragma unroll
      for (int nt = 0; nt < 4; nt++) {
        vh[nt] = *(const short8v*)&VHs[(nt << 4) + l16][(kk << 5) + (quad << 3)];
        vl[nt] = *(const short8v*)&VLs[(nt << 4) + l16][(kk << 5) + (quad << 3)];
      }
      #pragma unroll
      for (int mt = 0; mt < 2; mt++) {
        const float* prp = &PF[w32 + (mt << 4) + l16][(kk << 5) + (quad << 3)];
        float4v pa = *(const float4v*)prp;
        float4v pb = *(const float4v*)(prp + 4);
        short8v ph, pl;
        #pragma unroll
        for (int j = 0; j < 4; j++) {
          unsigned ua = __float_as_uint(pa[j]);
          unsigned ub = __float_as_uint(pb[j]);
          float la = pa[j] - __uint_as_float(ua & 0xffff0000u);
          float lb = pb[j] - __uint_as_float(ub & 0xffff0000u);
          ph[j]     = (short)(ua >> 16);
          ph[4 + j] = (short)(ub >> 16);
          pl[j]     = (short)(__float_as_uint(la) >> 16);
          pl[4 + j] = (short)(__float_as_uint(lb) >> 16);
        }
        #pragma unroll
        for (int nt = 0; nt < 4; nt++) {
          oacc[mt][nt] = __builtin_amdgcn_mfma_f32_16x16x32_bf16(ph, vh[nt], oacc[mt][nt], 0, 0, 0);
          oacc[mt][nt] = __builtin_amdgcn_mfma_f32_16x16x32_bf16(ph, vl[nt], oacc[mt][nt], 0, 0, 0);
          oacc[mt][nt] = __builtin_amdgcn_mfma_f32_16x16x32_bf16(pl, vh[nt], oacc[mt][nt], 0, 0, 0);
        }
      }
    }
  }

  // ---- one l-reduction over the 16 l16 lanes (same quad = same rows) ----
  #pragma unroll
  for (int mt = 0; mt < 2; mt++)
    #pragma unroll
    for (int r = 0; r < 4; r++) {
      float l = lsum[mt][r];
      #pragma unroll
      for (int o = 8; o >= 1; o >>= 1) l += __shfl_xor(l, o);
      lsum[mt][r] = l;
    }

  // ---- epilogue: o = O/l, split hi/lo, write [b][s][h][hd] ----
  #pragma unroll
  for (int mt = 0; mt < 2; mt++)
    #pragma unroll
    for (int r = 0; r < 4; r++) {
      float invl = 1.0f / lsum[mt][r];
      int srow = q0 + w32 + (mt << 4) + (quad << 2) + r;
      u64 gbase = ((u64)(b * Sdim + srow) * Hdim + h) * HDdim;
      #pragma unroll
      for (int nt = 0; nt < 4; nt++) {
        float o = oacc[mt][nt][r] * invl;
        ushort_t t = f2bf(o);
        OHI[gbase + (nt << 4) + l16] = t;
        OLO[gbase + (nt << 4) + l16] = f2bf(o - bf2f(t));
      }
    }
}

// ---------------------------------------------------------------------------
// elementwise stages
// ---------------------------------------------------------------------------
__global__ __launch_bounds__(256) void add_qdq_kernel(
    const float* __restrict__ a, const float* __restrict__ amaxA,
    const float* __restrict__ x, float* __restrict__ outp, u64 n,
    float* __restrict__ amaxOut)
{
  const float aA = *amaxA;
  u64 i = (u64)blockIdx.x * 256 + threadIdx.x;
  u64 stride = (u64)gridDim.x * 256;
  float m = 0.0f;
  for (; i < n; i += stride) {
    float t = qdq_f(a[i], aA) + x[i];
    outp[i] = t;
    m = fmaxf(m, fabsf(t));
  }
  m = blockMax256(m);
  if (threadIdx.x == 0) atomicMaxF(amaxOut, m);
}

__global__ __launch_bounds__(256) void qdq_out_kernel(
    const float* __restrict__ u, const float* __restrict__ amaxU,
    float* __restrict__ o, u64 n)
{
  const float aU = *amaxU;
  u64 i = (u64)blockIdx.x * 256 + threadIdx.x;
  u64 stride = (u64)gridDim.x * 256;
  for (; i < n; i += stride) o[i] = qdq_f(u[i], aU);
}

// ---------------------------------------------------------------------------
// launch
// ---------------------------------------------------------------------------
extern "C" void kernel_launch(void* const* d_in, const int* in_sizes, int n_in,
                              void* d_out, int out_size, void* d_ws, size_t ws_size,
                              hipStream_t stream)
{
  const float* x   = (const float*)d_in[0];
  const float* g1  = (const float*)d_in[1];
  const float* bn1 = (const float*)d_in[2];
  const float* Wq  = (const float*)d_in[3];
  const float* bq  = (const float*)d_in[4];
  const float* Wk  = (const float*)d_in[5];
  const float* bk  = (const float*)d_in[6];
  const float* Wv  = (const float*)d_in[7];
  const float* bv  = (const float*)d_in[8];
  const float* Wo  = (const float*)d_in[9];
  const float* bo  = (const float*)d_in[10];
  const float* g2  = (const float*)d_in[11];
  const float* bn2 = (const float*)d_in[12];
  const float* W1  = (const float*)d_in[13];
  const float* bf1 = (const float*)d_in[14];
  const float* W2  = (const float*)d_in[15];
  const float* bf2 = (const float*)d_in[16];
  float* out = (float*)d_out;

  const u64 NBSD = (u64)Bdim * Sdim * Ddim;     // 8,388,608
  const u64 NB4  = NBSD * 4;
  const u64 DD   = (u64)Ddim * Ddim;

  char* Wb = (char*)d_ws;
  float*       Sc   = (float*)Wb;                // 256 floats: 0-11 scales, 128.. KMX[64]
  float*       U0   = (float*)(Wb + 1024);
  float*       U1   = (float*)(Wb + 1024 + NB4);
  float*       F    = (float*)(Wb + 1024 + 2 * NB4);
  signed char* A8   = (signed char*)(Wb + 1024 + 6 * NB4);
  signed char* Wq8  = A8 + NBSD;
  signed char* Wk8  = Wq8 + DD;
  signed char* Wv8  = Wk8 + DD;
  signed char* W18  = Wv8 + DD;
  signed char* W28  = W18 + 4 * DD;
  ushort_t*    WoBF = (ushort_t*)(W28 + 4 * DD);
  float*       NQ   = (float*)(WoBF + DD);       // 64*2048 floats
  float*       KMX  = Sc + 128;

  // overlays (lifetime-checked):
  float* F0 = F;                                  // k fp32 (pre-attn), then o
  float* F1 = F + NBSD;                           // v fp32 (pre-attn)
  ushort_t* QHp = (ushort_t*)(F + 2 * NBSD);      // prep Q hi/lo in F2
  ushort_t* QLp = QHp + NBSD;
  ushort_t* KHp = (ushort_t*)(F + 3 * NBSD);      // prep K hi/lo in F3
  ushort_t* KLp = KHp + NBSD;
  ushort_t* VTH = (ushort_t*)U0;                  // prep V^T hi/lo in U0
  ushort_t* VTL = VTH + NBSD;
  ushort_t* OHI = (ushort_t*)U1;                  // attn out hi/lo in U1 (q dead)
  ushort_t* OLO = OHI + NBSD;
  signed char* G8 = (signed char*)U0;             // gelu int8 (h2 dead by then)

  const u64 needBytes = (u64)((char*)(NQ + (u64)64 * Sdim) - Wb);
  if (ws_size < needBytes) return;

  // scales: 0:h1 1:Wq 2:Wk 3:Wv 4:Wo 5:W1 6:W2 7:o_proj 8:t 9:h2 10:gelu 11:final
  init_scalars<<<1, 256, 0, stream>>>(Sc);

  ln_kernel<<<Bdim * Sdim, 256, 0, stream>>>(x, g1, bn1, nullptr, U0, Sc + 0);

  absmax6_kernel<<<3072, 256, 0, stream>>>(Wq, Wk, Wv, Wo, W1, W2, Sc);

  quant8_kernel<<<4096, 256, 0, stream>>>(U0, Sc + 0, A8, NBSD / 4);
  quantw_kernel<<<3840, 256, 0, stream>>>(Wq, Wk, Wv, Wo, W1, W2,
                                          Wq8, Wk8, Wv8, WoBF, W18, W28, Sc);

  const int M = Bdim * Sdim;                     // 8192
  dim3 gP(Ddim / 128, M / 128);                  // (8, 64)
  gemm_i8<0><<<gP, 256, 0, stream>>>(A8, Wq8, bq, U1, M, Ddim, Ddim, Sc + 0, Sc + 1, nullptr);
  gemm_i8<0><<<gP, 256, 0, stream>>>(A8, Wk8, bk, F0, M, Ddim, Ddim, Sc + 0, Sc + 2, nullptr);
  gemm_i8<0><<<gP, 256, 0, stream>>>(A8, Wv8, bv, F1, M, Ddim, Ddim, Sc + 0, Sc + 3, nullptr);

  dim3 gPrep(Sdim / 64, Bdim * Hdim);            // (32, 64)
  prep_attn<<<gPrep, 256, 0, stream>>>(U1, F0, F1, QHp, QLp, KHp, KLp, VTH, VTL, NQ, KMX);

  dim3 gAttn(Sdim / 128, Bdim * Hdim);           // (16, 64)
  attn_kernel<<<gAttn, 256, 0, stream>>>(QHp, QLp, KHp, KLp, VTH, VTL, NQ, KMX, OHI, OLO);

  gemm_bf16_wo<<<gP, 256, 0, stream>>>(OHI, OLO, WoBF, bo, F0, M, Ddim, Ddim, Sc + 4, Sc + 7);

  // t = fq(o) + x -> U1 (OHI/OLO dead)
  add_qdq_kernel<<<4096, 256, 0, stream>>>(F0, Sc + 7, x, U1, NBSD, Sc + 8);

  ln_kernel<<<Bdim * Sdim, 256, 0, stream>>>(U1, g2, bn2, Sc + 8, U0, Sc + 9);
  quant8_kernel<<<4096, 256, 0, stream>>>(U0, Sc + 9, A8, NBSD / 4);

  dim3 gF1(4 * Ddim / 128, M / 128);             // (32, 64)
  gemm_i8<1><<<gF1, 256, 0, stream>>>(A8, W18, bf1, F, M, 4 * Ddim, Ddim, Sc + 9, Sc + 5, Sc + 10);

  quant8_kernel<<<4096, 256, 0, stream>>>(F, Sc + 10, G8, NBSD);

  // FFN2 with fused residual: u = acc*s + bias + qdq(t) -> d_out, amax Sc11
  gemm_i8<2><<<gP, 256, 0, stream>>>(G8, W28, bf2, out, M, Ddim, 4 * Ddim,
                                     Sc + 10, Sc + 6, Sc + 11, U1, Sc + 8);

  qdq_out_kernel<<<4096, 256, 0, stream>>>(out, Sc + 11, out, NBSD);
}